// Round 6
// baseline (432.704 us; speedup 1.0000x reference)
//
#include <hip/hip_runtime.h>
#include <cstdint>
#include <cstddef>

#define FEAT 128
#define FOUT 40
constexpr float BN_EPS = 1e-5f;

typedef __attribute__((ext_vector_type(8))) short bf16x8;
typedef __attribute__((ext_vector_type(4))) float f32x4;
typedef unsigned u32x4 __attribute__((ext_vector_type(4)));
typedef float f32x4v __attribute__((ext_vector_type(4)));

__device__ __forceinline__ unsigned short f2bf(float f) {
    unsigned u = __float_as_uint(f);
    u += 0x7FFFu + ((u >> 16) & 1u);
    return (unsigned short)(u >> 16);
}
__device__ __forceinline__ float bflo(unsigned u) { return __uint_as_float(u << 16); }
__device__ __forceinline__ float bfhi(unsigned u) { return __uint_as_float(u & 0xFFFF0000u); }
__device__ __forceinline__ unsigned packbf2(float a, float b) {
    return (unsigned)f2bf(a) | ((unsigned)f2bf(b) << 16);
}
__device__ __forceinline__ void nt_store_u4(uint4* p, uint4 v) {
    u32x4 w; w[0] = v.x; w[1] = v.y; w[2] = v.z; w[3] = v.w;
    __builtin_nontemporal_store(w, (u32x4*)p);
}
__device__ __forceinline__ void nt_store_f4(float* p, float a, float b, float c, float d) {
    f32x4v w; w[0] = a; w[1] = b; w[2] = c; w[3] = d;
    __builtin_nontemporal_store(w, (f32x4v*)p);
}

// ---------------- CSR build ----------------

__global__ __launch_bounds__(256) void count_k(const int* __restrict__ dst, int* __restrict__ cnt, int E) {
    int e = blockIdx.x * 256 + threadIdx.x;
    if (e < E) atomicAdd(&cnt[dst[e]], 1);
}

__global__ __launch_bounds__(256) void scan1_k(const int* __restrict__ cnt, int* __restrict__ bsum, int n) {
    __shared__ int sh[256];
    int base = blockIdx.x * 1024, t = threadIdx.x;
    int s = 0;
#pragma unroll
    for (int j = 0; j < 4; ++j) {
        int idx = base + t * 4 + j;
        if (idx < n) s += cnt[idx];
    }
    sh[t] = s;
    __syncthreads();
    for (int o = 128; o > 0; o >>= 1) {
        if (t < o) sh[t] += sh[t + o];
        __syncthreads();
    }
    if (t == 0) bsum[blockIdx.x] = sh[0];
}

__global__ void scan2_k(const int* __restrict__ bsum, int* __restrict__ boff, int nb,
                        int* __restrict__ offs, int n, int E) {
    __shared__ int sh[256];
    int t = threadIdx.x;
    if (nb <= 256) {
        int v = (t < nb) ? bsum[t] : 0;
        sh[t] = v;
        __syncthreads();
        for (int o = 1; o < 256; o <<= 1) {
            int x = (t >= o) ? sh[t - o] : 0;
            __syncthreads();
            sh[t] += x;
            __syncthreads();
        }
        if (t < nb) boff[t] = sh[t] - v;
        if (t == 0) offs[n] = E;
    } else if (t == 0) {
        int run = 0;
        for (int i = 0; i < nb; ++i) { boff[i] = run; run += bsum[i]; }
        offs[n] = E;
    }
}

// scan3 also emits cursor and dinv (merged cursor_dinv_k)
__global__ __launch_bounds__(256) void scan3_k(const int* __restrict__ cnt, const int* __restrict__ boff,
                                               int* __restrict__ offs, int* __restrict__ cursor,
                                               float* __restrict__ dinv, int n) {
    __shared__ int sh[256];
    int base = blockIdx.x * 1024, t = threadIdx.x;
    int c[4];
    int s = 0;
#pragma unroll
    for (int j = 0; j < 4; ++j) {
        int idx = base + t * 4 + j;
        c[j] = (idx < n) ? cnt[idx] : 0;
        s += c[j];
    }
    sh[t] = s;
    __syncthreads();
    for (int o = 1; o < 256; o <<= 1) {
        int v = (t >= o) ? sh[t - o] : 0;
        __syncthreads();
        sh[t] += v;
        __syncthreads();
    }
    int g = boff[blockIdx.x] + sh[t] - s;
#pragma unroll
    for (int j = 0; j < 4; ++j) {
        int idx = base + t * 4 + j;
        if (idx < n) {
            offs[idx] = g;
            cursor[idx] = g;
            dinv[idx] = rsqrtf((float)(c[j] + 1));
        }
        g += c[j];
    }
}

__global__ __launch_bounds__(256) void fill_k(const int* __restrict__ src, const int* __restrict__ dst,
                                              int* __restrict__ cursor, int* __restrict__ csr, int E) {
    int e = blockIdx.x * 256 + threadIdx.x;
    if (e < E) {
        int d = dst[e];
        int p = atomicAdd(&cursor[d], 1);
        csr[p] = src[e];
    }
}

// ---------------- weight pack to bf16 MFMA B-fragment order ----------------

__global__ __launch_bounds__(256) void castW_k(const float* __restrict__ W1, const float* __restrict__ W2,
                                               const float* __restrict__ W3,
                                               unsigned short* __restrict__ Wt1, unsigned short* __restrict__ Wt2,
                                               unsigned short* __restrict__ Wt3) {
    int tid = blockIdx.x * 256 + threadIdx.x;
    int stride = gridDim.x * 256;
    for (int i = tid; i < 4 * 4 * 128 * 8; i += stride) {
        int j = i & 7, c = (i >> 3) & 127, q = (i >> 10) & 3, kt = i >> 12;
        int k = kt * 32 + q * 8 + j;
        Wt1[i] = f2bf(W1[k * 128 + c]);
        Wt2[i] = f2bf(W2[k * 128 + c]);
    }
    for (int i = tid; i < 4 * 4 * 48 * 8; i += stride) {
        int j = i & 7, rest = i >> 3;
        int c = rest % 48, kq = rest / 48;
        int q = kq & 3, kt = kq >> 2;
        int k = kt * 32 + q * 8 + j;
        Wt3[i] = (c < FOUT) ? f2bf(W3[k * FOUT + c]) : (unsigned short)0;
    }
}

// ---------------- MFMA GEMM 128x128, epilogue * dinv, bf16 out ----------------

template <int SRC>
__global__ __launch_bounds__(256, 3) void gemm128_k(const void* __restrict__ srcp,
                                                    const unsigned short* __restrict__ Wt,
                                                    const float* __restrict__ ss,
                                                    const float* __restrict__ dinv,
                                                    unsigned short* __restrict__ Hb,
                                                    int ntiles, int nreal) {
    __shared__ uint4 XsU[64 * 16];
    unsigned short* Xs = (unsigned short*)XsU;

    const int t = threadIdx.x;
    const int tc = t & 15;
    const int l = t & 63, w = t >> 6;
    const int wm = w >> 1, wn = w & 1;
    const int lr = l & 15, q = l >> 4;

    float sc[8], sh[8];
    if (SRC == 1) {
#pragma unroll
        for (int j = 0; j < 8; ++j) { sc[j] = ss[tc * 8 + j]; sh[j] = ss[128 + tc * 8 + j]; }
    }

    bf16x8 Bf[4][4];
#pragma unroll
    for (int kt = 0; kt < 4; ++kt)
#pragma unroll
        for (int n = 0; n < 4; ++n) {
            int col = wn * 64 + n * 16 + lr;
            Bf[kt][n] = *(const bf16x8*)&((const uint4*)Wt)[(kt * 4 + q) * 128 + col];
        }

    for (int tile = blockIdx.x; tile < ntiles; tile += gridDim.x) {
        const int row0 = tile * 64;
        __syncthreads();
#pragma unroll
        for (int k2 = 0; k2 < 4; ++k2) {
            int row = (t >> 4) + k2 * 16;
            int grow = row0 + row;
            uint4 o;
            if (SRC == 0) {
                if (grow < nreal) {
                    const float4* xp = (const float4*)((const float*)srcp + (size_t)grow * FEAT + tc * 8);
                    float4 f0 = xp[0], f1 = xp[1];
                    o.x = packbf2(f0.x, f0.y); o.y = packbf2(f0.z, f0.w);
                    o.z = packbf2(f1.x, f1.y); o.w = packbf2(f1.z, f1.w);
                } else {
                    o.x = 0u; o.y = 0u; o.z = 0u; o.w = 0u;
                }
            } else {
                uint4 u = ((const uint4*)((const unsigned short*)srcp + (size_t)grow * FEAT))[tc];
                float v0 = fmaxf(fmaf(bflo(u.x), sc[0], sh[0]), 0.f);
                float v1 = fmaxf(fmaf(bfhi(u.x), sc[1], sh[1]), 0.f);
                float v2 = fmaxf(fmaf(bflo(u.y), sc[2], sh[2]), 0.f);
                float v3 = fmaxf(fmaf(bfhi(u.y), sc[3], sh[3]), 0.f);
                float v4 = fmaxf(fmaf(bflo(u.z), sc[4], sh[4]), 0.f);
                float v5 = fmaxf(fmaf(bfhi(u.z), sc[5], sh[5]), 0.f);
                float v6 = fmaxf(fmaf(bflo(u.w), sc[6], sh[6]), 0.f);
                float v7 = fmaxf(fmaf(bfhi(u.w), sc[7], sh[7]), 0.f);
                o.x = packbf2(v0, v1); o.y = packbf2(v2, v3);
                o.z = packbf2(v4, v5); o.w = packbf2(v6, v7);
            }
            XsU[row * 16 + (tc ^ (row & 7))] = o;
        }
        __syncthreads();

        f32x4 acc[2][4];
#pragma unroll
        for (int m = 0; m < 2; ++m)
#pragma unroll
            for (int n = 0; n < 4; ++n)
#pragma unroll
                for (int r2 = 0; r2 < 4; ++r2) acc[m][n][r2] = 0.f;

#pragma unroll
        for (int kt = 0; kt < 4; ++kt) {
            int rowA = wm * 32 + lr;
            bf16x8 A0 = *(const bf16x8*)&XsU[rowA * 16 + ((kt * 4 + q) ^ (rowA & 7))];
            int rowB = rowA + 16;
            bf16x8 A1 = *(const bf16x8*)&XsU[rowB * 16 + ((kt * 4 + q) ^ (rowB & 7))];
#pragma unroll
            for (int n = 0; n < 4; ++n) {
                acc[0][n] = __builtin_amdgcn_mfma_f32_16x16x32_bf16(A0, Bf[kt][n], acc[0][n], 0, 0, 0);
                acc[1][n] = __builtin_amdgcn_mfma_f32_16x16x32_bf16(A1, Bf[kt][n], acc[1][n], 0, 0, 0);
            }
        }
        __syncthreads();

#pragma unroll
        for (int m = 0; m < 2; ++m) {
            float dv[4];
#pragma unroll
            for (int r = 0; r < 4; ++r) dv[r] = dinv[row0 + wm * 32 + m * 16 + q * 4 + r];
#pragma unroll
            for (int n = 0; n < 4; ++n) {
                int col = wn * 64 + n * 16 + lr;
#pragma unroll
                for (int r = 0; r < 4; ++r) {
                    int row = wm * 32 + m * 16 + q * 4 + r;
                    Xs[row * 128 + (((col >> 3) ^ (row & 7)) << 3) + (col & 7)] = f2bf(acc[m][n][r] * dv[r]);
                }
            }
        }
        __syncthreads();
#pragma unroll
        for (int k2 = 0; k2 < 4; ++k2) {
            int row = (t >> 4) + k2 * 16;
            ((uint4*)&Hb[(size_t)(row0 + row) * FEAT])[tc] = XsU[row * 16 + (tc ^ (row & 7))];
        }
    }
}

// ---------------- MFMA GEMM 128x40 (padded to 48), fused BN+ReLU on load ----------------

__global__ __launch_bounds__(256, 4) void gemm40_k(const unsigned short* __restrict__ srcp,
                                                   const unsigned short* __restrict__ Wt,
                                                   const float* __restrict__ ss,
                                                   const float* __restrict__ dinv,
                                                   unsigned short* __restrict__ H3,
                                                   int ntiles) {
    __shared__ uint4 XsU[64 * 16];
    unsigned short* Xs = (unsigned short*)XsU;
    const int t = threadIdx.x, tc = t & 15;
    const int l = t & 63, w = t >> 6, lr = l & 15, q = l >> 4;

    float sc[8], sh[8];
#pragma unroll
    for (int j = 0; j < 8; ++j) { sc[j] = ss[tc * 8 + j]; sh[j] = ss[128 + tc * 8 + j]; }

    bf16x8 Bf[4][3];
#pragma unroll
    for (int kt = 0; kt < 4; ++kt)
#pragma unroll
        for (int n = 0; n < 3; ++n)
            Bf[kt][n] = *(const bf16x8*)&((const uint4*)Wt)[(kt * 4 + q) * 48 + n * 16 + lr];

    for (int tile = blockIdx.x; tile < ntiles; tile += gridDim.x) {
        const int row0 = tile * 64;
        __syncthreads();
#pragma unroll
        for (int k2 = 0; k2 < 4; ++k2) {
            int row = (t >> 4) + k2 * 16;
            int grow = row0 + row;
            uint4 u = ((const uint4*)(srcp + (size_t)grow * FEAT))[tc];
            float v0 = fmaxf(fmaf(bflo(u.x), sc[0], sh[0]), 0.f);
            float v1 = fmaxf(fmaf(bfhi(u.x), sc[1], sh[1]), 0.f);
            float v2 = fmaxf(fmaf(bflo(u.y), sc[2], sh[2]), 0.f);
            float v3 = fmaxf(fmaf(bfhi(u.y), sc[3], sh[3]), 0.f);
            float v4 = fmaxf(fmaf(bflo(u.z), sc[4], sh[4]), 0.f);
            float v5 = fmaxf(fmaf(bfhi(u.z), sc[5], sh[5]), 0.f);
            float v6 = fmaxf(fmaf(bflo(u.w), sc[6], sh[6]), 0.f);
            float v7 = fmaxf(fmaf(bfhi(u.w), sc[7], sh[7]), 0.f);
            uint4 o;
            o.x = packbf2(v0, v1); o.y = packbf2(v2, v3);
            o.z = packbf2(v4, v5); o.w = packbf2(v6, v7);
            XsU[row * 16 + (tc ^ (row & 7))] = o;
        }
        __syncthreads();

        f32x4 acc[3];
#pragma unroll
        for (int n = 0; n < 3; ++n)
#pragma unroll
            for (int r2 = 0; r2 < 4; ++r2) acc[n][r2] = 0.f;

#pragma unroll
        for (int kt = 0; kt < 4; ++kt) {
            int row = w * 16 + lr;
            bf16x8 A = *(const bf16x8*)&XsU[row * 16 + ((kt * 4 + q) ^ (row & 7))];
#pragma unroll
            for (int n = 0; n < 3; ++n)
                acc[n] = __builtin_amdgcn_mfma_f32_16x16x32_bf16(A, Bf[kt][n], acc[n], 0, 0, 0);
        }
        __syncthreads();

        float dv[4];
#pragma unroll
        for (int r = 0; r < 4; ++r) dv[r] = dinv[row0 + w * 16 + q * 4 + r];
#pragma unroll
        for (int n = 0; n < 3; ++n) {
            int col = n * 16 + lr;
#pragma unroll
            for (int r = 0; r < 4; ++r) {
                int row = w * 16 + q * 4 + r;
                Xs[row * 128 + (((col >> 3) ^ (row & 7)) << 3) + (col & 7)] = f2bf(acc[n][r] * dv[r]);
            }
        }
        __syncthreads();
        for (int i = t; i < 384; i += 256) {
            int row = i / 6, cc = i - row * 6;
            ((uint4*)&H3[(size_t)(row0 + row) * 64])[cc] = XsU[row * 16 + (cc ^ (row & 7))];
        }
    }
}

// ---------------- aggregation: 16-lane group x 2 nodes, masked gathers, NT stores ----------------

__global__ __launch_bounds__(256, 4) void agg128_k(const uint4* __restrict__ Hb4, const int* __restrict__ offs,
                                                   const int* __restrict__ csr, const float* __restrict__ dinv,
                                                   const float* __restrict__ bias, uint4* __restrict__ Zb4,
                                                   float* __restrict__ sums, int n) {
    const int t = threadIdx.x;
    const int g16 = t >> 4, l16 = t & 15;
    const int wid = t >> 6, l = t & 63;

    const int nodeA = blockIdx.x * 32 + g16;
    const int nodeB = nodeA + 16;
    const bool vA = nodeA < n, vB = nodeB < n;

    int begA = 0, endA = 0, begB = 0, endB = 0;
    if (vA) { begA = offs[nodeA]; endA = offs[nodeA + 1]; }
    if (vB) { begB = offs[nodeB]; endB = offs[nodeB + 1]; }

    float aA[8] = {0.f,0.f,0.f,0.f,0.f,0.f,0.f,0.f};
    float aB[8] = {0.f,0.f,0.f,0.f,0.f,0.f,0.f,0.f};
    if (vA) {
        uint4 u = Hb4[(size_t)nodeA * 16 + l16];
        aA[0]=bflo(u.x); aA[1]=bfhi(u.x); aA[2]=bflo(u.y); aA[3]=bfhi(u.y);
        aA[4]=bflo(u.z); aA[5]=bfhi(u.z); aA[6]=bflo(u.w); aA[7]=bfhi(u.w);
    }
    if (vB) {
        uint4 u = Hb4[(size_t)nodeB * 16 + l16];
        aB[0]=bflo(u.x); aB[1]=bfhi(u.x); aB[2]=bflo(u.y); aB[3]=bfhi(u.y);
        aB[4]=bflo(u.z); aB[5]=bfhi(u.z); aB[6]=bflo(u.w); aB[7]=bfhi(u.w);
    }

    int eA = begA, eB = begB;
    while (eA < endA || eB < endB) {
        int remA = endA - eA, remB = endB - eB;
        int iA[8], iB[8];
#pragma unroll
        for (int k = 0; k < 8; ++k) { iA[k] = -1; if (k < remA) iA[k] = csr[eA + k]; }
#pragma unroll
        for (int k = 0; k < 8; ++k) { iB[k] = -1; if (k < remB) iB[k] = csr[eB + k]; }
        uint4 gA[8], gB[8];
#pragma unroll
        for (int k = 0; k < 8; ++k) {
            gA[k].x = gA[k].y = gA[k].z = gA[k].w = 0u;
            if (iA[k] >= 0) gA[k] = Hb4[(size_t)iA[k] * 16 + l16];
        }
#pragma unroll
        for (int k = 0; k < 8; ++k) {
            gB[k].x = gB[k].y = gB[k].z = gB[k].w = 0u;
            if (iB[k] >= 0) gB[k] = Hb4[(size_t)iB[k] * 16 + l16];
        }
#pragma unroll
        for (int k = 0; k < 8; ++k) {
            aA[0]+=bflo(gA[k].x); aA[1]+=bfhi(gA[k].x); aA[2]+=bflo(gA[k].y); aA[3]+=bfhi(gA[k].y);
            aA[4]+=bflo(gA[k].z); aA[5]+=bfhi(gA[k].z); aA[6]+=bflo(gA[k].w); aA[7]+=bfhi(gA[k].w);
            aB[0]+=bflo(gB[k].x); aB[1]+=bfhi(gB[k].x); aB[2]+=bflo(gB[k].y); aB[3]+=bfhi(gB[k].y);
            aB[4]+=bflo(gB[k].z); aB[5]+=bfhi(gB[k].z); aB[6]+=bflo(gB[k].w); aB[7]+=bfhi(gB[k].w);
        }
        eA += 8; eB += 8;
    }

    float bs[8];
#pragma unroll
    for (int j = 0; j < 8; ++j) bs[j] = bias[l16 * 8 + j];
    float dvA = vA ? dinv[nodeA] : 0.f;
    float dvB = vB ? dinv[nodeB] : 0.f;
    float s[8], qq[8];
#pragma unroll
    for (int j = 0; j < 8; ++j) {
        float zA = fmaf(aA[j], dvA, bs[j]);
        float zB = fmaf(aB[j], dvB, bs[j]);
        aA[j] = zA; aB[j] = zB;
        float sA = vA ? zA : 0.f, sB = vB ? zB : 0.f;
        s[j] = sA + sB;
        qq[j] = sA * sA + sB * sB;
    }
    if (vA) {
        uint4 o;
        o.x = packbf2(aA[0], aA[1]); o.y = packbf2(aA[2], aA[3]);
        o.z = packbf2(aA[4], aA[5]); o.w = packbf2(aA[6], aA[7]);
        nt_store_u4(&Zb4[(size_t)nodeA * 16 + l16], o);
    }
    if (vB) {
        uint4 o;
        o.x = packbf2(aB[0], aB[1]); o.y = packbf2(aB[2], aB[3]);
        o.z = packbf2(aB[4], aB[5]); o.w = packbf2(aB[6], aB[7]);
        nt_store_u4(&Zb4[(size_t)nodeB * 16 + l16], o);
    }

    // BN stats: cross-group shfl reduce, then tiny LDS + one atomic per feature per block
#pragma unroll
    for (int j = 0; j < 8; ++j) {
        s[j] += __shfl_xor(s[j], 16);
        s[j] += __shfl_xor(s[j], 32);
        qq[j] += __shfl_xor(qq[j], 16);
        qq[j] += __shfl_xor(qq[j], 32);
    }
    __shared__ float red[4][16][16];   // [wave][l16][8 sum | 8 sq]
    if (l < 16) {
#pragma unroll
        for (int j = 0; j < 8; ++j) {
            red[wid][l][j] = s[j];
            red[wid][l][8 + j] = qq[j];
        }
    }
    __syncthreads();
    int f = t & 127, which = t >> 7;
    float acc = 0.f;
#pragma unroll
    for (int ww = 0; ww < 4; ++ww) acc += red[ww][f >> 3][which * 8 + (f & 7)];
    atomicAdd(&sums[which * 128 + f], acc);
}

__global__ void bnfinal_k(const float* __restrict__ sums, const float* __restrict__ g,
                          const float* __restrict__ be, float* __restrict__ ss, int n) {
    int c = threadIdx.x;
    float inv_n = 1.0f / (float)n;
    float mu = sums[c] * inv_n;
    float var = sums[128 + c] * inv_n - mu * mu;
    float rstd = rsqrtf(var + BN_EPS);
    float scv = g[c] * rstd;
    ss[c] = scv;
    ss[128 + c] = be[c] - mu * scv;
}

// ---------------- layer-3 aggregation: 8-lane group per node (8 nodes/wave), masked gathers ----------------

__global__ __launch_bounds__(256, 4) void agg40_k(const uint4* __restrict__ H34, const int* __restrict__ offs,
                                                  const int* __restrict__ csr, const float* __restrict__ dinv,
                                                  const float* __restrict__ bias, float* __restrict__ out, int n) {
    const int t = threadIdx.x;
    const int g8 = t >> 3, l8 = t & 7;     // group of 8 lanes; lane covers cols l8*8..+7
    const int node = blockIdx.x * 32 + g8;
    if (node >= n) return;                 // whole 8-lane group exits together

    int beg = offs[node], end = offs[node + 1];
    uint4 u = H34[(size_t)node * 8 + l8];
    float a[8];
    a[0]=bflo(u.x); a[1]=bfhi(u.x); a[2]=bflo(u.y); a[3]=bfhi(u.y);
    a[4]=bflo(u.z); a[5]=bfhi(u.z); a[6]=bflo(u.w); a[7]=bfhi(u.w);

    for (int e = beg; e < end; e += 8) {
        int rem = end - e;
        int idx[8];
#pragma unroll
        for (int k = 0; k < 8; ++k) { idx[k] = -1; if (k < rem) idx[k] = csr[e + k]; }
        uint4 v[8];
#pragma unroll
        for (int k = 0; k < 8; ++k) {
            v[k].x = v[k].y = v[k].z = v[k].w = 0u;
            if (idx[k] >= 0) v[k] = H34[(size_t)idx[k] * 8 + l8];
        }
#pragma unroll
        for (int k = 0; k < 8; ++k) {
            a[0]+=bflo(v[k].x); a[1]+=bfhi(v[k].x); a[2]+=bflo(v[k].y); a[3]+=bfhi(v[k].y);
            a[4]+=bflo(v[k].z); a[5]+=bfhi(v[k].z); a[6]+=bflo(v[k].w); a[7]+=bfhi(v[k].w);
        }
    }

    float dv = dinv[node];
    float val[8];
    float m = -INFINITY;
#pragma unroll
    for (int j = 0; j < 8; ++j) {
        int fj = l8 * 8 + j;
        val[j] = (fj < FOUT) ? fmaf(a[j], dv, bias[fj]) : -INFINITY;
        m = fmaxf(m, val[j]);
    }
#pragma unroll
    for (int o = 4; o > 0; o >>= 1) m = fmaxf(m, __shfl_xor(m, o, 8));
    float es = 0.f;
#pragma unroll
    for (int j = 0; j < 8; ++j) es += (l8 * 8 + j < FOUT) ? expf(val[j] - m) : 0.f;
#pragma unroll
    for (int o = 4; o > 0; o >>= 1) es += __shfl_xor(es, o, 8);
    float lse = m + logf(es);
    if (l8 < 5) {  // features l8*8..+7 all < 40
        float* op = out + (size_t)node * FOUT + l8 * 8;
        nt_store_f4(op,     val[0]-lse, val[1]-lse, val[2]-lse, val[3]-lse);
        nt_store_f4(op + 4, val[4]-lse, val[5]-lse, val[6]-lse, val[7]-lse);
    }
}

// ---------------- launch ----------------

extern "C" void kernel_launch(void* const* d_in, const int* in_sizes, int n_in,
                              void* d_out, int out_size, void* d_ws, size_t ws_size,
                              hipStream_t stream) {
    const float* x   = (const float*)d_in[0];
    const int*   src = (const int*)d_in[1];
    const int*   dst = (const int*)d_in[2];
    const float* W1  = (const float*)d_in[3];
    const float* b1  = (const float*)d_in[4];
    const float* W2  = (const float*)d_in[5];
    const float* b2  = (const float*)d_in[6];
    const float* W3  = (const float*)d_in[7];
    const float* b3  = (const float*)d_in[8];
    const float* g1  = (const float*)d_in[9];
    const float* be1 = (const float*)d_in[10];
    const float* g2  = (const float*)d_in[11];
    const float* be2 = (const float*)d_in[12];

    const int N = in_sizes[0] / FEAT;
    const int E = in_sizes[1];
    const int Np = (N + 63) & ~63;
    const int ntiles = Np / 64;
    float* out = (float*)d_out;

    char* p = (char*)d_ws;
    auto alloc = [&](size_t bytes) {
        char* r = p;
        p += (bytes + 255) & ~(size_t)255;
        return r;
    };
    float* dinv   = (float*)alloc((size_t)Np * 4);
    int*   cnt    = (int*)alloc((size_t)N * 4);
    int*   offs   = (int*)alloc((size_t)(N + 1) * 4);
    int*   cursor = (int*)alloc((size_t)N * 4);
    int*   csr    = (int*)alloc((size_t)E * 4);
    int*   bsum   = (int*)alloc(1024);
    int*   boff   = (int*)alloc(1024);
    float* sums   = (float*)alloc(1024);
    float* ss     = (float*)alloc(1024);
    unsigned short* Wt1 = (unsigned short*)alloc(4 * 4 * 128 * 8 * 2);
    unsigned short* Wt2 = (unsigned short*)alloc(4 * 4 * 128 * 8 * 2);
    unsigned short* Wt3 = (unsigned short*)alloc(4 * 4 * 48 * 8 * 2);
    unsigned short* Hb  = (unsigned short*)alloc((size_t)Np * FEAT * 2);
    unsigned short* Zb  = (unsigned short*)alloc((size_t)Np * FEAT * 2);
    unsigned short* H3  = (unsigned short*)alloc((size_t)Np * 64 * 2);

    const int nb = (N + 1023) / 1024;
    const int eb = (E + 255) / 256;
    const int ab = (N + 31) / 32;     // agg grids: 32 nodes per block

    // CSR build + dinv
    hipMemsetAsync(cnt, 0, (size_t)N * 4, stream);
    count_k<<<eb, 256, 0, stream>>>(dst, cnt, E);
    scan1_k<<<nb, 256, 0, stream>>>(cnt, bsum, N);
    scan2_k<<<1, 256, 0, stream>>>(bsum, boff, nb, offs, N, E);
    scan3_k<<<nb, 256, 0, stream>>>(cnt, boff, offs, cursor, dinv, N);
    fill_k<<<eb, 256, 0, stream>>>(src, dst, cursor, csr, E);
    castW_k<<<48, 256, 0, stream>>>(W1, W2, W3, Wt1, Wt2, Wt3);

    // Layer 1
    gemm128_k<0><<<768, 256, 0, stream>>>(x, Wt1, nullptr, dinv, Hb, ntiles, N);
    hipMemsetAsync(sums, 0, 1024, stream);
    agg128_k<<<ab, 256, 0, stream>>>((const uint4*)Hb, offs, csr, dinv, b1, (uint4*)Zb, sums, N);
    bnfinal_k<<<1, 128, 0, stream>>>(sums, g1, be1, ss, N);

    // Layer 2 (BN1+ReLU fused into staging)
    gemm128_k<1><<<768, 256, 0, stream>>>(Zb, Wt2, ss, dinv, Hb, ntiles, N);
    hipMemsetAsync(sums, 0, 1024, stream);
    agg128_k<<<ab, 256, 0, stream>>>((const uint4*)Hb, offs, csr, dinv, b2, (uint4*)Zb, sums, N);
    bnfinal_k<<<1, 128, 0, stream>>>(sums, g2, be2, ss, N);

    // Layer 3 (BN2+ReLU fused into staging) + log_softmax
    gemm40_k<<<1024, 256, 0, stream>>>(Zb, Wt3, ss, dinv, H3, ntiles);
    agg40_k<<<ab, 256, 0, stream>>>((const uint4*)H3, offs, csr, dinv, b3, out, N);
}

// Round 7
// 430.793 us; speedup vs baseline: 1.0044x; 1.0044x over previous
//
#include <hip/hip_runtime.h>
#include <cstdint>
#include <cstddef>

#define FEAT 128
#define FOUT 40
constexpr float BN_EPS = 1e-5f;

typedef __attribute__((ext_vector_type(8))) short bf16x8;
typedef __attribute__((ext_vector_type(4))) float f32x4;

__device__ __forceinline__ unsigned short f2bf(float f) {
    unsigned u = __float_as_uint(f);
    u += 0x7FFFu + ((u >> 16) & 1u);
    return (unsigned short)(u >> 16);
}
__device__ __forceinline__ float bflo(unsigned u) { return __uint_as_float(u << 16); }
__device__ __forceinline__ float bfhi(unsigned u) { return __uint_as_float(u & 0xFFFF0000u); }
__device__ __forceinline__ unsigned packbf2(float a, float b) {
    return (unsigned)f2bf(a) | ((unsigned)f2bf(b) << 16);
}

// ---------------- CSR build ----------------

__global__ __launch_bounds__(256) void count_k(const int* __restrict__ dst, int* __restrict__ cnt, int E) {
    int e = blockIdx.x * 256 + threadIdx.x;
    if (e < E) atomicAdd(&cnt[dst[e]], 1);
}

__global__ __launch_bounds__(256) void scan1_k(const int* __restrict__ cnt, int* __restrict__ bsum, int n) {
    __shared__ int sh[256];
    int base = blockIdx.x * 1024, t = threadIdx.x;
    int s = 0;
#pragma unroll
    for (int j = 0; j < 4; ++j) {
        int idx = base + t * 4 + j;
        if (idx < n) s += cnt[idx];
    }
    sh[t] = s;
    __syncthreads();
    for (int o = 128; o > 0; o >>= 1) {
        if (t < o) sh[t] += sh[t + o];
        __syncthreads();
    }
    if (t == 0) bsum[blockIdx.x] = sh[0];
}

__global__ void scan2_k(const int* __restrict__ bsum, int* __restrict__ boff, int nb,
                        int* __restrict__ offs, int n, int E) {
    __shared__ int sh[256];
    int t = threadIdx.x;
    if (nb <= 256) {
        int v = (t < nb) ? bsum[t] : 0;
        sh[t] = v;
        __syncthreads();
        for (int o = 1; o < 256; o <<= 1) {
            int x = (t >= o) ? sh[t - o] : 0;
            __syncthreads();
            sh[t] += x;
            __syncthreads();
        }
        if (t < nb) boff[t] = sh[t] - v;
        if (t == 0) offs[n] = E;
    } else if (t == 0) {
        int run = 0;
        for (int i = 0; i < nb; ++i) { boff[i] = run; run += bsum[i]; }
        offs[n] = E;
    }
}

// scan3 also emits cursor and dinv
__global__ __launch_bounds__(256) void scan3_k(const int* __restrict__ cnt, const int* __restrict__ boff,
                                               int* __restrict__ offs, int* __restrict__ cursor,
                                               float* __restrict__ dinv, int n) {
    __shared__ int sh[256];
    int base = blockIdx.x * 1024, t = threadIdx.x;
    int c[4];
    int s = 0;
#pragma unroll
    for (int j = 0; j < 4; ++j) {
        int idx = base + t * 4 + j;
        c[j] = (idx < n) ? cnt[idx] : 0;
        s += c[j];
    }
    sh[t] = s;
    __syncthreads();
    for (int o = 1; o < 256; o <<= 1) {
        int v = (t >= o) ? sh[t - o] : 0;
        __syncthreads();
        sh[t] += v;
        __syncthreads();
    }
    int g = boff[blockIdx.x] + sh[t] - s;
#pragma unroll
    for (int j = 0; j < 4; ++j) {
        int idx = base + t * 4 + j;
        if (idx < n) {
            offs[idx] = g;
            cursor[idx] = g;
            dinv[idx] = rsqrtf((float)(c[j] + 1));
        }
        g += c[j];
    }
}

__global__ __launch_bounds__(256) void fill_k(const int* __restrict__ src, const int* __restrict__ dst,
                                              int* __restrict__ cursor, int* __restrict__ csr, int E) {
    int e = blockIdx.x * 256 + threadIdx.x;
    if (e < E) {
        int d = dst[e];
        int p = atomicAdd(&cursor[d], 1);
        csr[p] = src[e];
    }
}

// ---------------- weight pack to bf16 MFMA B-fragment order ----------------

__global__ __launch_bounds__(256) void castW_k(const float* __restrict__ W1, const float* __restrict__ W2,
                                               const float* __restrict__ W3,
                                               unsigned short* __restrict__ Wt1, unsigned short* __restrict__ Wt2,
                                               unsigned short* __restrict__ Wt3) {
    int tid = blockIdx.x * 256 + threadIdx.x;
    int stride = gridDim.x * 256;
    for (int i = tid; i < 4 * 4 * 128 * 8; i += stride) {
        int j = i & 7, c = (i >> 3) & 127, q = (i >> 10) & 3, kt = i >> 12;
        int k = kt * 32 + q * 8 + j;
        Wt1[i] = f2bf(W1[k * 128 + c]);
        Wt2[i] = f2bf(W2[k * 128 + c]);
    }
    for (int i = tid; i < 4 * 4 * 48 * 8; i += stride) {
        int j = i & 7, rest = i >> 3;
        int c = rest % 48, kq = rest / 48;
        int q = kq & 3, kt = kq >> 2;
        int k = kt * 32 + q * 8 + j;
        Wt3[i] = (c < FOUT) ? f2bf(W3[k * FOUT + c]) : (unsigned short)0;
    }
}

// ---------------- MFMA GEMM 128x128, epilogue * dinv, bf16 out ----------------

template <int SRC>
__global__ __launch_bounds__(256, 3) void gemm128_k(const void* __restrict__ srcp,
                                                    const unsigned short* __restrict__ Wt,
                                                    const float* __restrict__ ss,
                                                    const float* __restrict__ dinv,
                                                    unsigned short* __restrict__ Hb,
                                                    int ntiles, int nreal) {
    __shared__ uint4 XsU[64 * 16];
    unsigned short* Xs = (unsigned short*)XsU;

    const int t = threadIdx.x;
    const int tc = t & 15;
    const int l = t & 63, w = t >> 6;
    const int wm = w >> 1, wn = w & 1;
    const int lr = l & 15, q = l >> 4;

    float sc[8], sh[8];
    if (SRC == 1) {
#pragma unroll
        for (int j = 0; j < 8; ++j) { sc[j] = ss[tc * 8 + j]; sh[j] = ss[128 + tc * 8 + j]; }
    }

    bf16x8 Bf[4][4];
#pragma unroll
    for (int kt = 0; kt < 4; ++kt)
#pragma unroll
        for (int n = 0; n < 4; ++n) {
            int col = wn * 64 + n * 16 + lr;
            Bf[kt][n] = *(const bf16x8*)&((const uint4*)Wt)[(kt * 4 + q) * 128 + col];
        }

    for (int tile = blockIdx.x; tile < ntiles; tile += gridDim.x) {
        const int row0 = tile * 64;
        __syncthreads();
#pragma unroll
        for (int k2 = 0; k2 < 4; ++k2) {
            int row = (t >> 4) + k2 * 16;
            int grow = row0 + row;
            uint4 o;
            if (SRC == 0) {
                if (grow < nreal) {
                    const float4* xp = (const float4*)((const float*)srcp + (size_t)grow * FEAT + tc * 8);
                    float4 f0 = xp[0], f1 = xp[1];
                    o.x = packbf2(f0.x, f0.y); o.y = packbf2(f0.z, f0.w);
                    o.z = packbf2(f1.x, f1.y); o.w = packbf2(f1.z, f1.w);
                } else {
                    o.x = 0u; o.y = 0u; o.z = 0u; o.w = 0u;
                }
            } else {
                uint4 u = ((const uint4*)((const unsigned short*)srcp + (size_t)grow * FEAT))[tc];
                float v0 = fmaxf(fmaf(bflo(u.x), sc[0], sh[0]), 0.f);
                float v1 = fmaxf(fmaf(bfhi(u.x), sc[1], sh[1]), 0.f);
                float v2 = fmaxf(fmaf(bflo(u.y), sc[2], sh[2]), 0.f);
                float v3 = fmaxf(fmaf(bfhi(u.y), sc[3], sh[3]), 0.f);
                float v4 = fmaxf(fmaf(bflo(u.z), sc[4], sh[4]), 0.f);
                float v5 = fmaxf(fmaf(bfhi(u.z), sc[5], sh[5]), 0.f);
                float v6 = fmaxf(fmaf(bflo(u.w), sc[6], sh[6]), 0.f);
                float v7 = fmaxf(fmaf(bfhi(u.w), sc[7], sh[7]), 0.f);
                o.x = packbf2(v0, v1); o.y = packbf2(v2, v3);
                o.z = packbf2(v4, v5); o.w = packbf2(v6, v7);
            }
            XsU[row * 16 + (tc ^ (row & 7))] = o;
        }
        __syncthreads();

        f32x4 acc[2][4];
#pragma unroll
        for (int m = 0; m < 2; ++m)
#pragma unroll
            for (int n = 0; n < 4; ++n)
#pragma unroll
                for (int r2 = 0; r2 < 4; ++r2) acc[m][n][r2] = 0.f;

#pragma unroll
        for (int kt = 0; kt < 4; ++kt) {
            int rowA = wm * 32 + lr;
            bf16x8 A0 = *(const bf16x8*)&XsU[rowA * 16 + ((kt * 4 + q) ^ (rowA & 7))];
            int rowB = rowA + 16;
            bf16x8 A1 = *(const bf16x8*)&XsU[rowB * 16 + ((kt * 4 + q) ^ (rowB & 7))];
#pragma unroll
            for (int n = 0; n < 4; ++n) {
                acc[0][n] = __builtin_amdgcn_mfma_f32_16x16x32_bf16(A0, Bf[kt][n], acc[0][n], 0, 0, 0);
                acc[1][n] = __builtin_amdgcn_mfma_f32_16x16x32_bf16(A1, Bf[kt][n], acc[1][n], 0, 0, 0);
            }
        }
        __syncthreads();

#pragma unroll
        for (int m = 0; m < 2; ++m) {
            float dv[4];
#pragma unroll
            for (int r = 0; r < 4; ++r) dv[r] = dinv[row0 + wm * 32 + m * 16 + q * 4 + r];
#pragma unroll
            for (int n = 0; n < 4; ++n) {
                int col = wn * 64 + n * 16 + lr;
#pragma unroll
                for (int r = 0; r < 4; ++r) {
                    int row = wm * 32 + m * 16 + q * 4 + r;
                    Xs[row * 128 + (((col >> 3) ^ (row & 7)) << 3) + (col & 7)] = f2bf(acc[m][n][r] * dv[r]);
                }
            }
        }
        __syncthreads();
#pragma unroll
        for (int k2 = 0; k2 < 4; ++k2) {
            int row = (t >> 4) + k2 * 16;
            ((uint4*)&Hb[(size_t)(row0 + row) * FEAT])[tc] = XsU[row * 16 + (tc ^ (row & 7))];
        }
    }
}

// ---------------- MFMA GEMM 128x40 (padded to 48), fused BN+ReLU on load ----------------

__global__ __launch_bounds__(256, 4) void gemm40_k(const unsigned short* __restrict__ srcp,
                                                   const unsigned short* __restrict__ Wt,
                                                   const float* __restrict__ ss,
                                                   const float* __restrict__ dinv,
                                                   unsigned short* __restrict__ H3,
                                                   int ntiles) {
    __shared__ uint4 XsU[64 * 16];
    unsigned short* Xs = (unsigned short*)XsU;
    const int t = threadIdx.x, tc = t & 15;
    const int l = t & 63, w = t >> 6, lr = l & 15, q = l >> 4;

    float sc[8], sh[8];
#pragma unroll
    for (int j = 0; j < 8; ++j) { sc[j] = ss[tc * 8 + j]; sh[j] = ss[128 + tc * 8 + j]; }

    bf16x8 Bf[4][3];
#pragma unroll
    for (int kt = 0; kt < 4; ++kt)
#pragma unroll
        for (int n = 0; n < 3; ++n)
            Bf[kt][n] = *(const bf16x8*)&((const uint4*)Wt)[(kt * 4 + q) * 48 + n * 16 + lr];

    for (int tile = blockIdx.x; tile < ntiles; tile += gridDim.x) {
        const int row0 = tile * 64;
        __syncthreads();
#pragma unroll
        for (int k2 = 0; k2 < 4; ++k2) {
            int row = (t >> 4) + k2 * 16;
            int grow = row0 + row;
            uint4 u = ((const uint4*)(srcp + (size_t)grow * FEAT))[tc];
            float v0 = fmaxf(fmaf(bflo(u.x), sc[0], sh[0]), 0.f);
            float v1 = fmaxf(fmaf(bfhi(u.x), sc[1], sh[1]), 0.f);
            float v2 = fmaxf(fmaf(bflo(u.y), sc[2], sh[2]), 0.f);
            float v3 = fmaxf(fmaf(bfhi(u.y), sc[3], sh[3]), 0.f);
            float v4 = fmaxf(fmaf(bflo(u.z), sc[4], sh[4]), 0.f);
            float v5 = fmaxf(fmaf(bfhi(u.z), sc[5], sh[5]), 0.f);
            float v6 = fmaxf(fmaf(bflo(u.w), sc[6], sh[6]), 0.f);
            float v7 = fmaxf(fmaf(bfhi(u.w), sc[7], sh[7]), 0.f);
            uint4 o;
            o.x = packbf2(v0, v1); o.y = packbf2(v2, v3);
            o.z = packbf2(v4, v5); o.w = packbf2(v6, v7);
            XsU[row * 16 + (tc ^ (row & 7))] = o;
        }
        __syncthreads();

        f32x4 acc[3];
#pragma unroll
        for (int n = 0; n < 3; ++n)
#pragma unroll
            for (int r2 = 0; r2 < 4; ++r2) acc[n][r2] = 0.f;

#pragma unroll
        for (int kt = 0; kt < 4; ++kt) {
            int row = w * 16 + lr;
            bf16x8 A = *(const bf16x8*)&XsU[row * 16 + ((kt * 4 + q) ^ (row & 7))];
#pragma unroll
            for (int n = 0; n < 3; ++n)
                acc[n] = __builtin_amdgcn_mfma_f32_16x16x32_bf16(A, Bf[kt][n], acc[n], 0, 0, 0);
        }
        __syncthreads();

        float dv[4];
#pragma unroll
        for (int r = 0; r < 4; ++r) dv[r] = dinv[row0 + w * 16 + q * 4 + r];
#pragma unroll
        for (int n = 0; n < 3; ++n) {
            int col = n * 16 + lr;
#pragma unroll
            for (int r = 0; r < 4; ++r) {
                int row = w * 16 + q * 4 + r;
                Xs[row * 128 + (((col >> 3) ^ (row & 7)) << 3) + (col & 7)] = f2bf(acc[n][r] * dv[r]);
            }
        }
        __syncthreads();
        for (int i = t; i < 384; i += 256) {
            int row = i / 6, cc = i - row * 6;
            ((uint4*)&H3[(size_t)(row0 + row) * 64])[cc] = XsU[row * 16 + (cc ^ (row & 7))];
        }
    }
}

// ---------------- aggregation: 16-lane group x 2 nodes, masked gathers, plain stores ----------------

__global__ __launch_bounds__(256, 4) void agg128_k(const uint4* __restrict__ Hb4, const int* __restrict__ offs,
                                                   const int* __restrict__ csr, const float* __restrict__ dinv,
                                                   const float* __restrict__ bias, uint4* __restrict__ Zb4,
                                                   float* __restrict__ sums, int n) {
    const int t = threadIdx.x;
    const int g16 = t >> 4, l16 = t & 15;
    const int wid = t >> 6, l = t & 63;

    const int nodeA = blockIdx.x * 32 + g16;
    const int nodeB = nodeA + 16;
    const bool vA = nodeA < n, vB = nodeB < n;

    int begA = 0, endA = 0, begB = 0, endB = 0;
    if (vA) { begA = offs[nodeA]; endA = offs[nodeA + 1]; }
    if (vB) { begB = offs[nodeB]; endB = offs[nodeB + 1]; }

    float aA[8] = {0.f,0.f,0.f,0.f,0.f,0.f,0.f,0.f};
    float aB[8] = {0.f,0.f,0.f,0.f,0.f,0.f,0.f,0.f};
    if (vA) {
        uint4 u = Hb4[(size_t)nodeA * 16 + l16];
        aA[0]=bflo(u.x); aA[1]=bfhi(u.x); aA[2]=bflo(u.y); aA[3]=bfhi(u.y);
        aA[4]=bflo(u.z); aA[5]=bfhi(u.z); aA[6]=bflo(u.w); aA[7]=bfhi(u.w);
    }
    if (vB) {
        uint4 u = Hb4[(size_t)nodeB * 16 + l16];
        aB[0]=bflo(u.x); aB[1]=bfhi(u.x); aB[2]=bflo(u.y); aB[3]=bfhi(u.y);
        aB[4]=bflo(u.z); aB[5]=bfhi(u.z); aB[6]=bflo(u.w); aB[7]=bfhi(u.w);
    }

    int eA = begA, eB = begB;
    while (eA < endA || eB < endB) {
        int remA = endA - eA, remB = endB - eB;
        int iA[8], iB[8];
#pragma unroll
        for (int k = 0; k < 8; ++k) { iA[k] = -1; if (k < remA) iA[k] = csr[eA + k]; }
#pragma unroll
        for (int k = 0; k < 8; ++k) { iB[k] = -1; if (k < remB) iB[k] = csr[eB + k]; }
        uint4 gA[8], gB[8];
#pragma unroll
        for (int k = 0; k < 8; ++k) {
            gA[k].x = gA[k].y = gA[k].z = gA[k].w = 0u;
            if (iA[k] >= 0) gA[k] = Hb4[(size_t)iA[k] * 16 + l16];
        }
#pragma unroll
        for (int k = 0; k < 8; ++k) {
            gB[k].x = gB[k].y = gB[k].z = gB[k].w = 0u;
            if (iB[k] >= 0) gB[k] = Hb4[(size_t)iB[k] * 16 + l16];
        }
#pragma unroll
        for (int k = 0; k < 8; ++k) {
            aA[0]+=bflo(gA[k].x); aA[1]+=bfhi(gA[k].x); aA[2]+=bflo(gA[k].y); aA[3]+=bfhi(gA[k].y);
            aA[4]+=bflo(gA[k].z); aA[5]+=bfhi(gA[k].z); aA[6]+=bflo(gA[k].w); aA[7]+=bfhi(gA[k].w);
            aB[0]+=bflo(gB[k].x); aB[1]+=bfhi(gB[k].x); aB[2]+=bflo(gB[k].y); aB[3]+=bfhi(gB[k].y);
            aB[4]+=bflo(gB[k].z); aB[5]+=bfhi(gB[k].z); aB[6]+=bflo(gB[k].w); aB[7]+=bfhi(gB[k].w);
        }
        eA += 8; eB += 8;
    }

    float bs[8];
#pragma unroll
    for (int j = 0; j < 8; ++j) bs[j] = bias[l16 * 8 + j];
    float dvA = vA ? dinv[nodeA] : 0.f;
    float dvB = vB ? dinv[nodeB] : 0.f;
    float s[8], qq[8];
#pragma unroll
    for (int j = 0; j < 8; ++j) {
        float zA = fmaf(aA[j], dvA, bs[j]);
        float zB = fmaf(aB[j], dvB, bs[j]);
        aA[j] = zA; aB[j] = zB;
        float sA = vA ? zA : 0.f, sB = vB ? zB : 0.f;
        s[j] = sA + sB;
        qq[j] = sA * sA + sB * sB;
    }
    if (vA) {
        uint4 o;
        o.x = packbf2(aA[0], aA[1]); o.y = packbf2(aA[2], aA[3]);
        o.z = packbf2(aA[4], aA[5]); o.w = packbf2(aA[6], aA[7]);
        Zb4[(size_t)nodeA * 16 + l16] = o;
    }
    if (vB) {
        uint4 o;
        o.x = packbf2(aB[0], aB[1]); o.y = packbf2(aB[2], aB[3]);
        o.z = packbf2(aB[4], aB[5]); o.w = packbf2(aB[6], aB[7]);
        Zb4[(size_t)nodeB * 16 + l16] = o;
    }

    // BN stats: cross-group shfl reduce, then tiny LDS + one atomic per feature per block
#pragma unroll
    for (int j = 0; j < 8; ++j) {
        s[j] += __shfl_xor(s[j], 16);
        s[j] += __shfl_xor(s[j], 32);
        qq[j] += __shfl_xor(qq[j], 16);
        qq[j] += __shfl_xor(qq[j], 32);
    }
    __shared__ float red[4][16][16];   // [wave][l16][8 sum | 8 sq]
    if (l < 16) {
#pragma unroll
        for (int j = 0; j < 8; ++j) {
            red[wid][l][j] = s[j];
            red[wid][l][8 + j] = qq[j];
        }
    }
    __syncthreads();
    int f = t & 127, which = t >> 7;
    float acc = 0.f;
#pragma unroll
    for (int ww = 0; ww < 4; ++ww) acc += red[ww][f >> 3][which * 8 + (f & 7)];
    atomicAdd(&sums[which * 128 + f], acc);
}

__global__ void bnfinal_k(const float* __restrict__ sums, const float* __restrict__ g,
                          const float* __restrict__ be, float* __restrict__ ss, int n) {
    int c = threadIdx.x;
    float inv_n = 1.0f / (float)n;
    float mu = sums[c] * inv_n;
    float var = sums[128 + c] * inv_n - mu * mu;
    float rstd = rsqrtf(var + BN_EPS);
    float scv = g[c] * rstd;
    ss[c] = scv;
    ss[128 + c] = be[c] - mu * scv;
}

// ---------------- layer-3 aggregation: 8-lane group per node, masked gathers ----------------

__global__ __launch_bounds__(256, 4) void agg40_k(const uint4* __restrict__ H34, const int* __restrict__ offs,
                                                  const int* __restrict__ csr, const float* __restrict__ dinv,
                                                  const float* __restrict__ bias, float* __restrict__ out, int n) {
    const int t = threadIdx.x;
    const int g8 = t >> 3, l8 = t & 7;
    const int node = blockIdx.x * 32 + g8;
    if (node >= n) return;

    int beg = offs[node], end = offs[node + 1];
    uint4 u = H34[(size_t)node * 8 + l8];
    float a[8];
    a[0]=bflo(u.x); a[1]=bfhi(u.x); a[2]=bflo(u.y); a[3]=bfhi(u.y);
    a[4]=bflo(u.z); a[5]=bfhi(u.z); a[6]=bflo(u.w); a[7]=bfhi(u.w);

    for (int e = beg; e < end; e += 8) {
        int rem = end - e;
        int idx[8];
#pragma unroll
        for (int k = 0; k < 8; ++k) { idx[k] = -1; if (k < rem) idx[k] = csr[e + k]; }
        uint4 v[8];
#pragma unroll
        for (int k = 0; k < 8; ++k) {
            v[k].x = v[k].y = v[k].z = v[k].w = 0u;
            if (idx[k] >= 0) v[k] = H34[(size_t)idx[k] * 8 + l8];
        }
#pragma unroll
        for (int k = 0; k < 8; ++k) {
            a[0]+=bflo(v[k].x); a[1]+=bfhi(v[k].x); a[2]+=bflo(v[k].y); a[3]+=bfhi(v[k].y);
            a[4]+=bflo(v[k].z); a[5]+=bfhi(v[k].z); a[6]+=bflo(v[k].w); a[7]+=bfhi(v[k].w);
        }
    }

    float dv = dinv[node];
    float val[8];
    float m = -INFINITY;
#pragma unroll
    for (int j = 0; j < 8; ++j) {
        int fj = l8 * 8 + j;
        val[j] = (fj < FOUT) ? fmaf(a[j], dv, bias[fj]) : -INFINITY;
        m = fmaxf(m, val[j]);
    }
#pragma unroll
    for (int o = 4; o > 0; o >>= 1) m = fmaxf(m, __shfl_xor(m, o, 8));
    float es = 0.f;
#pragma unroll
    for (int j = 0; j < 8; ++j) es += (l8 * 8 + j < FOUT) ? expf(val[j] - m) : 0.f;
#pragma unroll
    for (int o = 4; o > 0; o >>= 1) es += __shfl_xor(es, o, 8);
    float lse = m + logf(es);
    if (l8 < 5) {
        float4 o0 = make_float4(val[0]-lse, val[1]-lse, val[2]-lse, val[3]-lse);
        float4 o1 = make_float4(val[4]-lse, val[5]-lse, val[6]-lse, val[7]-lse);
        float* op = out + (size_t)node * FOUT + l8 * 8;
        *(float4*)op = o0;
        *(float4*)(op + 4) = o1;
    }
}

// ---------------- launch ----------------

extern "C" void kernel_launch(void* const* d_in, const int* in_sizes, int n_in,
                              void* d_out, int out_size, void* d_ws, size_t ws_size,
                              hipStream_t stream) {
    const float* x   = (const float*)d_in[0];
    const int*   src = (const int*)d_in[1];
    const int*   dst = (const int*)d_in[2];
    const float* W1  = (const float*)d_in[3];
    const float* b1  = (const float*)d_in[4];
    const float* W2  = (const float*)d_in[5];
    const float* b2  = (const float*)d_in[6];
    const float* W3  = (const float*)d_in[7];
    const float* b3  = (const float*)d_in[8];
    const float* g1  = (const float*)d_in[9];
    const float* be1 = (const float*)d_in[10];
    const float* g2  = (const float*)d_in[11];
    const float* be2 = (const float*)d_in[12];

    const int N = in_sizes[0] / FEAT;
    const int E = in_sizes[1];
    const int Np = (N + 63) & ~63;
    const int ntiles = Np / 64;
    float* out = (float*)d_out;

    char* p = (char*)d_ws;
    auto alloc = [&](size_t bytes) {
        char* r = p;
        p += (bytes + 255) & ~(size_t)255;
        return r;
    };
    float* dinv   = (float*)alloc((size_t)Np * 4);
    int*   cnt    = (int*)alloc((size_t)N * 4);
    int*   offs   = (int*)alloc((size_t)(N + 1) * 4);
    int*   cursor = (int*)alloc((size_t)N * 4);
    int*   csr    = (int*)alloc((size_t)E * 4);
    int*   bsum   = (int*)alloc(1024);
    int*   boff   = (int*)alloc(1024);
    float* sums   = (float*)alloc(1024);
    float* ss     = (float*)alloc(1024);
    unsigned short* Wt1 = (unsigned short*)alloc(4 * 4 * 128 * 8 * 2);
    unsigned short* Wt2 = (unsigned short*)alloc(4 * 4 * 128 * 8 * 2);
    unsigned short* Wt3 = (unsigned short*)alloc(4 * 4 * 48 * 8 * 2);
    unsigned short* Hb  = (unsigned short*)alloc((size_t)Np * FEAT * 2);
    unsigned short* Zb  = (unsigned short*)alloc((size_t)Np * FEAT * 2);
    unsigned short* H3  = (unsigned short*)alloc((size_t)Np * 64 * 2);

    const int nb = (N + 1023) / 1024;
    const int eb = (E + 255) / 256;
    const int ab = (N + 31) / 32;

    // CSR build + dinv
    hipMemsetAsync(cnt, 0, (size_t)N * 4, stream);
    count_k<<<eb, 256, 0, stream>>>(dst, cnt, E);
    scan1_k<<<nb, 256, 0, stream>>>(cnt, bsum, N);
    scan2_k<<<1, 256, 0, stream>>>(bsum, boff, nb, offs, N, E);
    scan3_k<<<nb, 256, 0, stream>>>(cnt, boff, offs, cursor, dinv, N);
    fill_k<<<eb, 256, 0, stream>>>(src, dst, cursor, csr, E);
    castW_k<<<48, 256, 0, stream>>>(W1, W2, W3, Wt1, Wt2, Wt3);

    // Layer 1
    gemm128_k<0><<<768, 256, 0, stream>>>(x, Wt1, nullptr, dinv, Hb, ntiles, N);
    hipMemsetAsync(sums, 0, 1024, stream);
    agg128_k<<<ab, 256, 0, stream>>>((const uint4*)Hb, offs, csr, dinv, b1, (uint4*)Zb, sums, N);
    bnfinal_k<<<1, 128, 0, stream>>>(sums, g1, be1, ss, N);

    // Layer 2 (BN1+ReLU fused into staging)
    gemm128_k<1><<<768, 256, 0, stream>>>(Zb, Wt2, ss, dinv, Hb, ntiles, N);
    hipMemsetAsync(sums, 0, 1024, stream);
    agg128_k<<<ab, 256, 0, stream>>>((const uint4*)Hb, offs, csr, dinv, b2, (uint4*)Zb, sums, N);
    bnfinal_k<<<1, 128, 0, stream>>>(sums, g2, be2, ss, N);

    // Layer 3 (BN2+ReLU fused into staging) + log_softmax
    gemm40_k<<<1024, 256, 0, stream>>>(Zb, Wt3, ss, dinv, H3, ntiles);
    agg40_k<<<ab, 256, 0, stream>>>((const uint4*)H3, offs, csr, dinv, b3, out, N);
}

// Round 8
// 337.725 us; speedup vs baseline: 1.2812x; 1.2756x over previous
//
#include <hip/hip_runtime.h>
#include <cstdint>
#include <cstddef>

#define FEAT 128
#define FOUT 40
constexpr float BN_EPS = 1e-5f;

typedef __attribute__((ext_vector_type(8))) short bf16x8;
typedef __attribute__((ext_vector_type(4))) float f32x4;

__device__ __forceinline__ unsigned short f2bf(float f) {
    unsigned u = __float_as_uint(f);
    u += 0x7FFFu + ((u >> 16) & 1u);
    return (unsigned short)(u >> 16);
}
__device__ __forceinline__ float bflo(unsigned u) { return __uint_as_float(u << 16); }
__device__ __forceinline__ float bfhi(unsigned u) { return __uint_as_float(u & 0xFFFF0000u); }
__device__ __forceinline__ unsigned packbf2(float a, float b) {
    return (unsigned)f2bf(a) | ((unsigned)f2bf(b) << 16);
}

// ---------------- CSR build ----------------

__global__ __launch_bounds__(256) void count_k(const int* __restrict__ dst, int* __restrict__ cnt, int E) {
    int e = blockIdx.x * 256 + threadIdx.x;
    if (e < E) atomicAdd(&cnt[dst[e]], 1);
}

__global__ __launch_bounds__(256) void scan1_k(const int* __restrict__ cnt, int* __restrict__ bsum, int n) {
    __shared__ int sh[256];
    int base = blockIdx.x * 1024, t = threadIdx.x;
    int s = 0;
#pragma unroll
    for (int j = 0; j < 4; ++j) {
        int idx = base + t * 4 + j;
        if (idx < n) s += cnt[idx];
    }
    sh[t] = s;
    __syncthreads();
    for (int o = 128; o > 0; o >>= 1) {
        if (t < o) sh[t] += sh[t + o];
        __syncthreads();
    }
    if (t == 0) bsum[blockIdx.x] = sh[0];
}

__global__ void scan2_k(const int* __restrict__ bsum, int* __restrict__ boff, int nb,
                        int* __restrict__ offs, int n, int E) {
    __shared__ int sh[256];
    int t = threadIdx.x;
    if (nb <= 256) {
        int v = (t < nb) ? bsum[t] : 0;
        sh[t] = v;
        __syncthreads();
        for (int o = 1; o < 256; o <<= 1) {
            int x = (t >= o) ? sh[t - o] : 0;
            __syncthreads();
            sh[t] += x;
            __syncthreads();
        }
        if (t < nb) boff[t] = sh[t] - v;
        if (t == 0) offs[n] = E;
    } else if (t == 0) {
        int run = 0;
        for (int i = 0; i < nb; ++i) { boff[i] = run; run += bsum[i]; }
        offs[n] = E;
    }
}

// scan3 also emits cursor and dinv
__global__ __launch_bounds__(256) void scan3_k(const int* __restrict__ cnt, const int* __restrict__ boff,
                                               int* __restrict__ offs, int* __restrict__ cursor,
                                               float* __restrict__ dinv, int n) {
    __shared__ int sh[256];
    int base = blockIdx.x * 1024, t = threadIdx.x;
    int c[4];
    int s = 0;
#pragma unroll
    for (int j = 0; j < 4; ++j) {
        int idx = base + t * 4 + j;
        c[j] = (idx < n) ? cnt[idx] : 0;
        s += c[j];
    }
    sh[t] = s;
    __syncthreads();
    for (int o = 1; o < 256; o <<= 1) {
        int v = (t >= o) ? sh[t - o] : 0;
        __syncthreads();
        sh[t] += v;
        __syncthreads();
    }
    int g = boff[blockIdx.x] + sh[t] - s;
#pragma unroll
    for (int j = 0; j < 4; ++j) {
        int idx = base + t * 4 + j;
        if (idx < n) {
            offs[idx] = g;
            cursor[idx] = g;
            dinv[idx] = rsqrtf((float)(c[j] + 1));
        }
        g += c[j];
    }
}

__global__ __launch_bounds__(256) void fill_k(const int* __restrict__ src, const int* __restrict__ dst,
                                              int* __restrict__ cursor, int* __restrict__ csr, int E) {
    int e = blockIdx.x * 256 + threadIdx.x;
    if (e < E) {
        int d = dst[e];
        int p = atomicAdd(&cursor[d], 1);
        csr[p] = src[e];
    }
}

// ---------------- weight pack to bf16 MFMA B-fragment order ----------------

__global__ __launch_bounds__(256) void castW_k(const float* __restrict__ W1, const float* __restrict__ W2,
                                               const float* __restrict__ W3,
                                               unsigned short* __restrict__ Wt1, unsigned short* __restrict__ Wt2,
                                               unsigned short* __restrict__ Wt3) {
    int tid = blockIdx.x * 256 + threadIdx.x;
    int stride = gridDim.x * 256;
    for (int i = tid; i < 4 * 4 * 128 * 8; i += stride) {
        int j = i & 7, c = (i >> 3) & 127, q = (i >> 10) & 3, kt = i >> 12;
        int k = kt * 32 + q * 8 + j;
        Wt1[i] = f2bf(W1[k * 128 + c]);
        Wt2[i] = f2bf(W2[k * 128 + c]);
    }
    for (int i = tid; i < 4 * 4 * 48 * 8; i += stride) {
        int j = i & 7, rest = i >> 3;
        int c = rest % 48, kq = rest / 48;
        int q = kq & 3, kt = kq >> 2;
        int k = kt * 32 + q * 8 + j;
        Wt3[i] = (c < FOUT) ? f2bf(W3[k * FOUT + c]) : (unsigned short)0;
    }
}

// ---------------- MFMA GEMM 128x128, epilogue * dinv, bf16 out ----------------

template <int SRC>
__global__ __launch_bounds__(256, 3) void gemm128_k(const void* __restrict__ srcp,
                                                    const unsigned short* __restrict__ Wt,
                                                    const float* __restrict__ ss,
                                                    const float* __restrict__ dinv,
                                                    unsigned short* __restrict__ Hb,
                                                    int ntiles, int nreal) {
    __shared__ uint4 XsU[64 * 16];
    unsigned short* Xs = (unsigned short*)XsU;

    const int t = threadIdx.x;
    const int tc = t & 15;
    const int l = t & 63, w = t >> 6;
    const int wm = w >> 1, wn = w & 1;
    const int lr = l & 15, q = l >> 4;

    float sc[8], sh[8];
    if (SRC == 1) {
#pragma unroll
        for (int j = 0; j < 8; ++j) { sc[j] = ss[tc * 8 + j]; sh[j] = ss[128 + tc * 8 + j]; }
    }

    bf16x8 Bf[4][4];
#pragma unroll
    for (int kt = 0; kt < 4; ++kt)
#pragma unroll
        for (int n = 0; n < 4; ++n) {
            int col = wn * 64 + n * 16 + lr;
            Bf[kt][n] = *(const bf16x8*)&((const uint4*)Wt)[(kt * 4 + q) * 128 + col];
        }

    for (int tile = blockIdx.x; tile < ntiles; tile += gridDim.x) {
        const int row0 = tile * 64;
        __syncthreads();
#pragma unroll
        for (int k2 = 0; k2 < 4; ++k2) {
            int row = (t >> 4) + k2 * 16;
            int grow = row0 + row;
            uint4 o;
            if (SRC == 0) {
                if (grow < nreal) {
                    const float4* xp = (const float4*)((const float*)srcp + (size_t)grow * FEAT + tc * 8);
                    float4 f0 = xp[0], f1 = xp[1];
                    o.x = packbf2(f0.x, f0.y); o.y = packbf2(f0.z, f0.w);
                    o.z = packbf2(f1.x, f1.y); o.w = packbf2(f1.z, f1.w);
                } else {
                    o.x = 0u; o.y = 0u; o.z = 0u; o.w = 0u;
                }
            } else {
                uint4 u = ((const uint4*)((const unsigned short*)srcp + (size_t)grow * FEAT))[tc];
                float v0 = fmaxf(fmaf(bflo(u.x), sc[0], sh[0]), 0.f);
                float v1 = fmaxf(fmaf(bfhi(u.x), sc[1], sh[1]), 0.f);
                float v2 = fmaxf(fmaf(bflo(u.y), sc[2], sh[2]), 0.f);
                float v3 = fmaxf(fmaf(bfhi(u.y), sc[3], sh[3]), 0.f);
                float v4 = fmaxf(fmaf(bflo(u.z), sc[4], sh[4]), 0.f);
                float v5 = fmaxf(fmaf(bfhi(u.z), sc[5], sh[5]), 0.f);
                float v6 = fmaxf(fmaf(bflo(u.w), sc[6], sh[6]), 0.f);
                float v7 = fmaxf(fmaf(bfhi(u.w), sc[7], sh[7]), 0.f);
                o.x = packbf2(v0, v1); o.y = packbf2(v2, v3);
                o.z = packbf2(v4, v5); o.w = packbf2(v6, v7);
            }
            XsU[row * 16 + (tc ^ (row & 7))] = o;
        }
        __syncthreads();

        f32x4 acc[2][4];
#pragma unroll
        for (int m = 0; m < 2; ++m)
#pragma unroll
            for (int n = 0; n < 4; ++n)
#pragma unroll
                for (int r2 = 0; r2 < 4; ++r2) acc[m][n][r2] = 0.f;

#pragma unroll
        for (int kt = 0; kt < 4; ++kt) {
            int rowA = wm * 32 + lr;
            bf16x8 A0 = *(const bf16x8*)&XsU[rowA * 16 + ((kt * 4 + q) ^ (rowA & 7))];
            int rowB = rowA + 16;
            bf16x8 A1 = *(const bf16x8*)&XsU[rowB * 16 + ((kt * 4 + q) ^ (rowB & 7))];
#pragma unroll
            for (int n = 0; n < 4; ++n) {
                acc[0][n] = __builtin_amdgcn_mfma_f32_16x16x32_bf16(A0, Bf[kt][n], acc[0][n], 0, 0, 0);
                acc[1][n] = __builtin_amdgcn_mfma_f32_16x16x32_bf16(A1, Bf[kt][n], acc[1][n], 0, 0, 0);
            }
        }
        __syncthreads();

#pragma unroll
        for (int m = 0; m < 2; ++m) {
            float dv[4];
#pragma unroll
            for (int r = 0; r < 4; ++r) dv[r] = dinv[row0 + wm * 32 + m * 16 + q * 4 + r];
#pragma unroll
            for (int n = 0; n < 4; ++n) {
                int col = wn * 64 + n * 16 + lr;
#pragma unroll
                for (int r = 0; r < 4; ++r) {
                    int row = wm * 32 + m * 16 + q * 4 + r;
                    Xs[row * 128 + (((col >> 3) ^ (row & 7)) << 3) + (col & 7)] = f2bf(acc[m][n][r] * dv[r]);
                }
            }
        }
        __syncthreads();
#pragma unroll
        for (int k2 = 0; k2 < 4; ++k2) {
            int row = (t >> 4) + k2 * 16;
            ((uint4*)&Hb[(size_t)(row0 + row) * FEAT])[tc] = XsU[row * 16 + (tc ^ (row & 7))];
        }
    }
}

// ---------------- MFMA GEMM 128x40 (padded to 48), fused BN+ReLU on load ----------------

__global__ __launch_bounds__(256, 4) void gemm40_k(const unsigned short* __restrict__ srcp,
                                                   const unsigned short* __restrict__ Wt,
                                                   const float* __restrict__ ss,
                                                   const float* __restrict__ dinv,
                                                   unsigned short* __restrict__ H3,
                                                   int ntiles) {
    __shared__ uint4 XsU[64 * 16];
    unsigned short* Xs = (unsigned short*)XsU;
    const int t = threadIdx.x, tc = t & 15;
    const int l = t & 63, w = t >> 6, lr = l & 15, q = l >> 4;

    float sc[8], sh[8];
#pragma unroll
    for (int j = 0; j < 8; ++j) { sc[j] = ss[tc * 8 + j]; sh[j] = ss[128 + tc * 8 + j]; }

    bf16x8 Bf[4][3];
#pragma unroll
    for (int kt = 0; kt < 4; ++kt)
#pragma unroll
        for (int n = 0; n < 3; ++n)
            Bf[kt][n] = *(const bf16x8*)&((const uint4*)Wt)[(kt * 4 + q) * 48 + n * 16 + lr];

    for (int tile = blockIdx.x; tile < ntiles; tile += gridDim.x) {
        const int row0 = tile * 64;
        __syncthreads();
#pragma unroll
        for (int k2 = 0; k2 < 4; ++k2) {
            int row = (t >> 4) + k2 * 16;
            int grow = row0 + row;
            uint4 u = ((const uint4*)(srcp + (size_t)grow * FEAT))[tc];
            float v0 = fmaxf(fmaf(bflo(u.x), sc[0], sh[0]), 0.f);
            float v1 = fmaxf(fmaf(bfhi(u.x), sc[1], sh[1]), 0.f);
            float v2 = fmaxf(fmaf(bflo(u.y), sc[2], sh[2]), 0.f);
            float v3 = fmaxf(fmaf(bfhi(u.y), sc[3], sh[3]), 0.f);
            float v4 = fmaxf(fmaf(bflo(u.z), sc[4], sh[4]), 0.f);
            float v5 = fmaxf(fmaf(bfhi(u.z), sc[5], sh[5]), 0.f);
            float v6 = fmaxf(fmaf(bflo(u.w), sc[6], sh[6]), 0.f);
            float v7 = fmaxf(fmaf(bfhi(u.w), sc[7], sh[7]), 0.f);
            uint4 o;
            o.x = packbf2(v0, v1); o.y = packbf2(v2, v3);
            o.z = packbf2(v4, v5); o.w = packbf2(v6, v7);
            XsU[row * 16 + (tc ^ (row & 7))] = o;
        }
        __syncthreads();

        f32x4 acc[3];
#pragma unroll
        for (int n = 0; n < 3; ++n)
#pragma unroll
            for (int r2 = 0; r2 < 4; ++r2) acc[n][r2] = 0.f;

#pragma unroll
        for (int kt = 0; kt < 4; ++kt) {
            int row = w * 16 + lr;
            bf16x8 A = *(const bf16x8*)&XsU[row * 16 + ((kt * 4 + q) ^ (row & 7))];
#pragma unroll
            for (int n = 0; n < 3; ++n)
                acc[n] = __builtin_amdgcn_mfma_f32_16x16x32_bf16(A, Bf[kt][n], acc[n], 0, 0, 0);
        }
        __syncthreads();

        float dv[4];
#pragma unroll
        for (int r = 0; r < 4; ++r) dv[r] = dinv[row0 + w * 16 + q * 4 + r];
#pragma unroll
        for (int n = 0; n < 3; ++n) {
            int col = n * 16 + lr;
#pragma unroll
            for (int r = 0; r < 4; ++r) {
                int row = w * 16 + q * 4 + r;
                Xs[row * 128 + (((col >> 3) ^ (row & 7)) << 3) + (col & 7)] = f2bf(acc[n][r] * dv[r]);
            }
        }
        __syncthreads();
        for (int i = t; i < 384; i += 256) {
            int row = i / 6, cc = i - row * 6;
            ((uint4*)&H3[(size_t)(row0 + row) * 64])[cc] = XsU[row * 16 + (cc ^ (row & 7))];
        }
    }
}

// ---------------- aggregation: 16-lane group, 2 nodes SEQUENTIALLY (low VGPR, no spill) ----------------

__global__ __launch_bounds__(256) void agg128_k(const uint4* __restrict__ Hb4, const int* __restrict__ offs,
                                                const int* __restrict__ csr, const float* __restrict__ dinv,
                                                const float* __restrict__ bias, uint4* __restrict__ Zb4,
                                                float* __restrict__ sums, int n) {
    const int t = threadIdx.x;
    const int g16 = t >> 4, l16 = t & 15;
    const int wid = t >> 6, l = t & 63;

    float bs[8];
#pragma unroll
    for (int j = 0; j < 8; ++j) bs[j] = bias[l16 * 8 + j];
    float s[8] = {0.f,0.f,0.f,0.f,0.f,0.f,0.f,0.f};
    float qq[8] = {0.f,0.f,0.f,0.f,0.f,0.f,0.f,0.f};

#pragma unroll
    for (int half = 0; half < 2; ++half) {
        const int node = blockIdx.x * 32 + half * 16 + g16;
        if (node < n) {
            int beg = offs[node], end = offs[node + 1];
            uint4 u = Hb4[(size_t)node * 16 + l16];
            float a[8];
            a[0]=bflo(u.x); a[1]=bfhi(u.x); a[2]=bflo(u.y); a[3]=bfhi(u.y);
            a[4]=bflo(u.z); a[5]=bfhi(u.z); a[6]=bflo(u.w); a[7]=bfhi(u.w);
            for (int e = beg; e < end; e += 8) {
                int rem = end - e;   // >= 1
                int idx[8];
#pragma unroll
                for (int k = 0; k < 8; ++k) idx[k] = (k < rem) ? csr[e + k] : -1;
                uint4 g[8];
#pragma unroll
                for (int k = 0; k < 8; ++k) {
                    g[k].x = g[k].y = g[k].z = g[k].w = 0u;
                    if (idx[k] >= 0) g[k] = Hb4[(size_t)idx[k] * 16 + l16];
                }
#pragma unroll
                for (int k = 0; k < 8; ++k) {
                    a[0]+=bflo(g[k].x); a[1]+=bfhi(g[k].x); a[2]+=bflo(g[k].y); a[3]+=bfhi(g[k].y);
                    a[4]+=bflo(g[k].z); a[5]+=bfhi(g[k].z); a[6]+=bflo(g[k].w); a[7]+=bfhi(g[k].w);
                }
            }
            float dv = dinv[node];
            float z[8];
#pragma unroll
            for (int j = 0; j < 8; ++j) {
                z[j] = fmaf(a[j], dv, bs[j]);
                s[j] += z[j];
                qq[j] += z[j] * z[j];
            }
            uint4 o;
            o.x = packbf2(z[0], z[1]); o.y = packbf2(z[2], z[3]);
            o.z = packbf2(z[4], z[5]); o.w = packbf2(z[6], z[7]);
            Zb4[(size_t)node * 16 + l16] = o;
        }
    }

    // BN stats: cross-group shfl reduce, then tiny LDS + one atomic per feature per block
#pragma unroll
    for (int j = 0; j < 8; ++j) {
        s[j] += __shfl_xor(s[j], 16);
        s[j] += __shfl_xor(s[j], 32);
        qq[j] += __shfl_xor(qq[j], 16);
        qq[j] += __shfl_xor(qq[j], 32);
    }
    __shared__ float red[4][16][16];   // [wave][l16][8 sum | 8 sq]
    if (l < 16) {
#pragma unroll
        for (int j = 0; j < 8; ++j) {
            red[wid][l][j] = s[j];
            red[wid][l][8 + j] = qq[j];
        }
    }
    __syncthreads();
    int f = t & 127, which = t >> 7;
    float acc = 0.f;
#pragma unroll
    for (int ww = 0; ww < 4; ++ww) acc += red[ww][f >> 3][which * 8 + (f & 7)];
    atomicAdd(&sums[which * 128 + f], acc);
}

__global__ void bnfinal_k(const float* __restrict__ sums, const float* __restrict__ g,
                          const float* __restrict__ be, float* __restrict__ ss, int n) {
    int c = threadIdx.x;
    float inv_n = 1.0f / (float)n;
    float mu = sums[c] * inv_n;
    float var = sums[128 + c] * inv_n - mu * mu;
    float rstd = rsqrtf(var + BN_EPS);
    float scv = g[c] * rstd;
    ss[c] = scv;
    ss[128 + c] = be[c] - mu * scv;
}

// ---------------- layer-3 aggregation: 8-lane group per node, masked gathers ----------------

__global__ __launch_bounds__(256) void agg40_k(const uint4* __restrict__ H34, const int* __restrict__ offs,
                                               const int* __restrict__ csr, const float* __restrict__ dinv,
                                               const float* __restrict__ bias, float* __restrict__ out, int n) {
    const int t = threadIdx.x;
    const int g8 = t >> 3, l8 = t & 7;
    const int node = blockIdx.x * 32 + g8;
    if (node >= n) return;

    int beg = offs[node], end = offs[node + 1];
    uint4 u = H34[(size_t)node * 8 + l8];
    float a[8];
    a[0]=bflo(u.x); a[1]=bfhi(u.x); a[2]=bflo(u.y); a[3]=bfhi(u.y);
    a[4]=bflo(u.z); a[5]=bfhi(u.z); a[6]=bflo(u.w); a[7]=bfhi(u.w);

    for (int e = beg; e < end; e += 8) {
        int rem = end - e;
        int idx[8];
#pragma unroll
        for (int k = 0; k < 8; ++k) idx[k] = (k < rem) ? csr[e + k] : -1;
        uint4 v[8];
#pragma unroll
        for (int k = 0; k < 8; ++k) {
            v[k].x = v[k].y = v[k].z = v[k].w = 0u;
            if (idx[k] >= 0) v[k] = H34[(size_t)idx[k] * 8 + l8];
        }
#pragma unroll
        for (int k = 0; k < 8; ++k) {
            a[0]+=bflo(v[k].x); a[1]+=bfhi(v[k].x); a[2]+=bflo(v[k].y); a[3]+=bfhi(v[k].y);
            a[4]+=bflo(v[k].z); a[5]+=bfhi(v[k].z); a[6]+=bflo(v[k].w); a[7]+=bfhi(v[k].w);
        }
    }

    float dv = dinv[node];
    float val[8];
    float m = -INFINITY;
#pragma unroll
    for (int j = 0; j < 8; ++j) {
        int fj = l8 * 8 + j;
        val[j] = (fj < FOUT) ? fmaf(a[j], dv, bias[fj]) : -INFINITY;
        m = fmaxf(m, val[j]);
    }
#pragma unroll
    for (int o = 4; o > 0; o >>= 1) m = fmaxf(m, __shfl_xor(m, o, 8));
    float es = 0.f;
#pragma unroll
    for (int j = 0; j < 8; ++j) es += (l8 * 8 + j < FOUT) ? expf(val[j] - m) : 0.f;
#pragma unroll
    for (int o = 4; o > 0; o >>= 1) es += __shfl_xor(es, o, 8);
    float lse = m + logf(es);
    if (l8 < 5) {
        float4 o0 = make_float4(val[0]-lse, val[1]-lse, val[2]-lse, val[3]-lse);
        float4 o1 = make_float4(val[4]-lse, val[5]-lse, val[6]-lse, val[7]-lse);
        float* op = out + (size_t)node * FOUT + l8 * 8;
        *(float4*)op = o0;
        *(float4*)(op + 4) = o1;
    }
}

// ---------------- launch ----------------

extern "C" void kernel_launch(void* const* d_in, const int* in_sizes, int n_in,
                              void* d_out, int out_size, void* d_ws, size_t ws_size,
                              hipStream_t stream) {
    const float* x   = (const float*)d_in[0];
    const int*   src = (const int*)d_in[1];
    const int*   dst = (const int*)d_in[2];
    const float* W1  = (const float*)d_in[3];
    const float* b1  = (const float*)d_in[4];
    const float* W2  = (const float*)d_in[5];
    const float* b2  = (const float*)d_in[6];
    const float* W3  = (const float*)d_in[7];
    const float* b3  = (const float*)d_in[8];
    const float* g1  = (const float*)d_in[9];
    const float* be1 = (const float*)d_in[10];
    const float* g2  = (const float*)d_in[11];
    const float* be2 = (const float*)d_in[12];

    const int N = in_sizes[0] / FEAT;
    const int E = in_sizes[1];
    const int Np = (N + 63) & ~63;
    const int ntiles = Np / 64;
    float* out = (float*)d_out;

    char* p = (char*)d_ws;
    auto alloc = [&](size_t bytes) {
        char* r = p;
        p += (bytes + 255) & ~(size_t)255;
        return r;
    };
    float* dinv   = (float*)alloc((size_t)Np * 4);
    int*   cnt    = (int*)alloc((size_t)N * 4);
    int*   offs   = (int*)alloc((size_t)(N + 1) * 4);
    int*   cursor = (int*)alloc((size_t)N * 4);
    int*   csr    = (int*)alloc((size_t)E * 4);
    int*   bsum   = (int*)alloc(1024);
    int*   boff   = (int*)alloc(1024);
    float* sums   = (float*)alloc(1024);
    float* ss     = (float*)alloc(1024);
    unsigned short* Wt1 = (unsigned short*)alloc(4 * 4 * 128 * 8 * 2);
    unsigned short* Wt2 = (unsigned short*)alloc(4 * 4 * 128 * 8 * 2);
    unsigned short* Wt3 = (unsigned short*)alloc(4 * 4 * 48 * 8 * 2);
    unsigned short* Hb  = (unsigned short*)alloc((size_t)Np * FEAT * 2);
    unsigned short* Zb  = (unsigned short*)alloc((size_t)Np * FEAT * 2);
    unsigned short* H3  = (unsigned short*)alloc((size_t)Np * 64 * 2);

    const int nb = (N + 1023) / 1024;
    const int eb = (E + 255) / 256;
    const int ab = (N + 31) / 32;   // 32 nodes per block for both agg kernels

    // CSR build + dinv
    hipMemsetAsync(cnt, 0, (size_t)N * 4, stream);
    count_k<<<eb, 256, 0, stream>>>(dst, cnt, E);
    scan1_k<<<nb, 256, 0, stream>>>(cnt, bsum, N);
    scan2_k<<<1, 256, 0, stream>>>(bsum, boff, nb, offs, N, E);
    scan3_k<<<nb, 256, 0, stream>>>(cnt, boff, offs, cursor, dinv, N);
    fill_k<<<eb, 256, 0, stream>>>(src, dst, cursor, csr, E);
    castW_k<<<48, 256, 0, stream>>>(W1, W2, W3, Wt1, Wt2, Wt3);

    // Layer 1
    gemm128_k<0><<<768, 256, 0, stream>>>(x, Wt1, nullptr, dinv, Hb, ntiles, N);
    hipMemsetAsync(sums, 0, 1024, stream);
    agg128_k<<<ab, 256, 0, stream>>>((const uint4*)Hb, offs, csr, dinv, b1, (uint4*)Zb, sums, N);
    bnfinal_k<<<1, 128, 0, stream>>>(sums, g1, be1, ss, N);

    // Layer 2 (BN1+ReLU fused into staging)
    gemm128_k<1><<<768, 256, 0, stream>>>(Zb, Wt2, ss, dinv, Hb, ntiles, N);
    hipMemsetAsync(sums, 0, 1024, stream);
    agg128_k<<<ab, 256, 0, stream>>>((const uint4*)Hb, offs, csr, dinv, b2, (uint4*)Zb, sums, N);
    bnfinal_k<<<1, 128, 0, stream>>>(sums, g2, be2, ss, N);

    // Layer 3 (BN2+ReLU fused into staging) + log_softmax
    gemm40_k<<<1024, 256, 0, stream>>>(Zb, Wt3, ss, dinv, H3, ntiles);
    agg40_k<<<ab, 256, 0, stream>>>((const uint4*)H3, offs, csr, dinv, b3, out, N);
}

// Round 9
// 335.889 us; speedup vs baseline: 1.2882x; 1.0055x over previous
//
#include <hip/hip_runtime.h>
#include <cstdint>
#include <cstddef>

#define FEAT 128
#define FOUT 40
constexpr float BN_EPS = 1e-5f;

typedef __attribute__((ext_vector_type(8))) short bf16x8;
typedef __attribute__((ext_vector_type(4))) float f32x4;

__device__ __forceinline__ unsigned short f2bf(float f) {
    unsigned u = __float_as_uint(f);
    u += 0x7FFFu + ((u >> 16) & 1u);
    return (unsigned short)(u >> 16);
}
__device__ __forceinline__ float bflo(unsigned u) { return __uint_as_float(u << 16); }
__device__ __forceinline__ float bfhi(unsigned u) { return __uint_as_float(u & 0xFFFF0000u); }
__device__ __forceinline__ unsigned packbf2(float a, float b) {
    return (unsigned)f2bf(a) | ((unsigned)f2bf(b) << 16);
}

// ---------------- CSR build ----------------

__global__ __launch_bounds__(256) void count_k(const int* __restrict__ dst, int* __restrict__ cnt, int E) {
    int e = blockIdx.x * 256 + threadIdx.x;
    if (e < E) atomicAdd(&cnt[dst[e]], 1);
}

__global__ __launch_bounds__(256) void scan1_k(const int* __restrict__ cnt, int* __restrict__ bsum, int n) {
    __shared__ int sh[256];
    int base = blockIdx.x * 1024, t = threadIdx.x;
    int s = 0;
#pragma unroll
    for (int j = 0; j < 4; ++j) {
        int idx = base + t * 4 + j;
        if (idx < n) s += cnt[idx];
    }
    sh[t] = s;
    __syncthreads();
    for (int o = 128; o > 0; o >>= 1) {
        if (t < o) sh[t] += sh[t + o];
        __syncthreads();
    }
    if (t == 0) bsum[blockIdx.x] = sh[0];
}

__global__ void scan2_k(const int* __restrict__ bsum, int* __restrict__ boff, int nb,
                        int* __restrict__ offs, int n, int E) {
    __shared__ int sh[256];
    int t = threadIdx.x;
    if (nb <= 256) {
        int v = (t < nb) ? bsum[t] : 0;
        sh[t] = v;
        __syncthreads();
        for (int o = 1; o < 256; o <<= 1) {
            int x = (t >= o) ? sh[t - o] : 0;
            __syncthreads();
            sh[t] += x;
            __syncthreads();
        }
        if (t < nb) boff[t] = sh[t] - v;
        if (t == 0) offs[n] = E;
    } else if (t == 0) {
        int run = 0;
        for (int i = 0; i < nb; ++i) { boff[i] = run; run += bsum[i]; }
        offs[n] = E;
    }
}

// scan3 also emits cursor and dinv
__global__ __launch_bounds__(256) void scan3_k(const int* __restrict__ cnt, const int* __restrict__ boff,
                                               int* __restrict__ offs, int* __restrict__ cursor,
                                               float* __restrict__ dinv, int n) {
    __shared__ int sh[256];
    int base = blockIdx.x * 1024, t = threadIdx.x;
    int c[4];
    int s = 0;
#pragma unroll
    for (int j = 0; j < 4; ++j) {
        int idx = base + t * 4 + j;
        c[j] = (idx < n) ? cnt[idx] : 0;
        s += c[j];
    }
    sh[t] = s;
    __syncthreads();
    for (int o = 1; o < 256; o <<= 1) {
        int v = (t >= o) ? sh[t - o] : 0;
        __syncthreads();
        sh[t] += v;
        __syncthreads();
    }
    int g = boff[blockIdx.x] + sh[t] - s;
#pragma unroll
    for (int j = 0; j < 4; ++j) {
        int idx = base + t * 4 + j;
        if (idx < n) {
            offs[idx] = g;
            cursor[idx] = g;
            dinv[idx] = rsqrtf((float)(c[j] + 1));
        }
        g += c[j];
    }
}

__global__ __launch_bounds__(256) void fill_k(const int* __restrict__ src, const int* __restrict__ dst,
                                              int* __restrict__ cursor, int* __restrict__ csr, int E) {
    int e = blockIdx.x * 256 + threadIdx.x;
    if (e < E) {
        int d = dst[e];
        int p = atomicAdd(&cursor[d], 1);
        csr[p] = src[e];
    }
}

// ---------------- weight pack to bf16 MFMA B-fragment order ----------------

__global__ __launch_bounds__(256) void castW_k(const float* __restrict__ W1, const float* __restrict__ W2,
                                               const float* __restrict__ W3,
                                               unsigned short* __restrict__ Wt1, unsigned short* __restrict__ Wt2,
                                               unsigned short* __restrict__ Wt3) {
    int tid = blockIdx.x * 256 + threadIdx.x;
    int stride = gridDim.x * 256;
    for (int i = tid; i < 4 * 4 * 128 * 8; i += stride) {
        int j = i & 7, c = (i >> 3) & 127, q = (i >> 10) & 3, kt = i >> 12;
        int k = kt * 32 + q * 8 + j;
        Wt1[i] = f2bf(W1[k * 128 + c]);
        Wt2[i] = f2bf(W2[k * 128 + c]);
    }
    for (int i = tid; i < 4 * 4 * 48 * 8; i += stride) {
        int j = i & 7, rest = i >> 3;
        int c = rest % 48, kq = rest / 48;
        int q = kq & 3, kt = kq >> 2;
        int k = kt * 32 + q * 8 + j;
        Wt3[i] = (c < FOUT) ? f2bf(W3[k * FOUT + c]) : (unsigned short)0;
    }
}

// ---------------- MFMA GEMM 128x128, epilogue * dinv, bf16 out ----------------

template <int SRC>
__global__ __launch_bounds__(256, 3) void gemm128_k(const void* __restrict__ srcp,
                                                    const unsigned short* __restrict__ Wt,
                                                    const float* __restrict__ ss,
                                                    const float* __restrict__ dinv,
                                                    unsigned short* __restrict__ Hb,
                                                    int ntiles, int nreal) {
    __shared__ uint4 XsU[64 * 16];
    unsigned short* Xs = (unsigned short*)XsU;

    const int t = threadIdx.x;
    const int tc = t & 15;
    const int l = t & 63, w = t >> 6;
    const int wm = w >> 1, wn = w & 1;
    const int lr = l & 15, q = l >> 4;

    float sc[8], sh[8];
    if (SRC == 1) {
#pragma unroll
        for (int j = 0; j < 8; ++j) { sc[j] = ss[tc * 8 + j]; sh[j] = ss[128 + tc * 8 + j]; }
    }

    bf16x8 Bf[4][4];
#pragma unroll
    for (int kt = 0; kt < 4; ++kt)
#pragma unroll
        for (int n = 0; n < 4; ++n) {
            int col = wn * 64 + n * 16 + lr;
            Bf[kt][n] = *(const bf16x8*)&((const uint4*)Wt)[(kt * 4 + q) * 128 + col];
        }

    for (int tile = blockIdx.x; tile < ntiles; tile += gridDim.x) {
        const int row0 = tile * 64;
        __syncthreads();
#pragma unroll
        for (int k2 = 0; k2 < 4; ++k2) {
            int row = (t >> 4) + k2 * 16;
            int grow = row0 + row;
            uint4 o;
            if (SRC == 0) {
                if (grow < nreal) {
                    const float4* xp = (const float4*)((const float*)srcp + (size_t)grow * FEAT + tc * 8);
                    float4 f0 = xp[0], f1 = xp[1];
                    o.x = packbf2(f0.x, f0.y); o.y = packbf2(f0.z, f0.w);
                    o.z = packbf2(f1.x, f1.y); o.w = packbf2(f1.z, f1.w);
                } else {
                    o.x = 0u; o.y = 0u; o.z = 0u; o.w = 0u;
                }
            } else {
                uint4 u = ((const uint4*)((const unsigned short*)srcp + (size_t)grow * FEAT))[tc];
                float v0 = fmaxf(fmaf(bflo(u.x), sc[0], sh[0]), 0.f);
                float v1 = fmaxf(fmaf(bfhi(u.x), sc[1], sh[1]), 0.f);
                float v2 = fmaxf(fmaf(bflo(u.y), sc[2], sh[2]), 0.f);
                float v3 = fmaxf(fmaf(bfhi(u.y), sc[3], sh[3]), 0.f);
                float v4 = fmaxf(fmaf(bflo(u.z), sc[4], sh[4]), 0.f);
                float v5 = fmaxf(fmaf(bfhi(u.z), sc[5], sh[5]), 0.f);
                float v6 = fmaxf(fmaf(bflo(u.w), sc[6], sh[6]), 0.f);
                float v7 = fmaxf(fmaf(bfhi(u.w), sc[7], sh[7]), 0.f);
                o.x = packbf2(v0, v1); o.y = packbf2(v2, v3);
                o.z = packbf2(v4, v5); o.w = packbf2(v6, v7);
            }
            XsU[row * 16 + (tc ^ (row & 7))] = o;
        }
        __syncthreads();

        f32x4 acc[2][4];
#pragma unroll
        for (int m = 0; m < 2; ++m)
#pragma unroll
            for (int n = 0; n < 4; ++n)
#pragma unroll
                for (int r2 = 0; r2 < 4; ++r2) acc[m][n][r2] = 0.f;

#pragma unroll
        for (int kt = 0; kt < 4; ++kt) {
            int rowA = wm * 32 + lr;
            bf16x8 A0 = *(const bf16x8*)&XsU[rowA * 16 + ((kt * 4 + q) ^ (rowA & 7))];
            int rowB = rowA + 16;
            bf16x8 A1 = *(const bf16x8*)&XsU[rowB * 16 + ((kt * 4 + q) ^ (rowB & 7))];
#pragma unroll
            for (int n = 0; n < 4; ++n) {
                acc[0][n] = __builtin_amdgcn_mfma_f32_16x16x32_bf16(A0, Bf[kt][n], acc[0][n], 0, 0, 0);
                acc[1][n] = __builtin_amdgcn_mfma_f32_16x16x32_bf16(A1, Bf[kt][n], acc[1][n], 0, 0, 0);
            }
        }
        __syncthreads();

#pragma unroll
        for (int m = 0; m < 2; ++m) {
            float dv[4];
#pragma unroll
            for (int r = 0; r < 4; ++r) dv[r] = dinv[row0 + wm * 32 + m * 16 + q * 4 + r];
#pragma unroll
            for (int n = 0; n < 4; ++n) {
                int col = wn * 64 + n * 16 + lr;
#pragma unroll
                for (int r = 0; r < 4; ++r) {
                    int row = wm * 32 + m * 16 + q * 4 + r;
                    Xs[row * 128 + (((col >> 3) ^ (row & 7)) << 3) + (col & 7)] = f2bf(acc[m][n][r] * dv[r]);
                }
            }
        }
        __syncthreads();
#pragma unroll
        for (int k2 = 0; k2 < 4; ++k2) {
            int row = (t >> 4) + k2 * 16;
            ((uint4*)&Hb[(size_t)(row0 + row) * FEAT])[tc] = XsU[row * 16 + (tc ^ (row & 7))];
        }
    }
}

// ---------------- MFMA GEMM 128x40 (padded to 48), fused BN+ReLU on load ----------------

__global__ __launch_bounds__(256, 4) void gemm40_k(const unsigned short* __restrict__ srcp,
                                                   const unsigned short* __restrict__ Wt,
                                                   const float* __restrict__ ss,
                                                   const float* __restrict__ dinv,
                                                   unsigned short* __restrict__ H3,
                                                   int ntiles) {
    __shared__ uint4 XsU[64 * 16];
    unsigned short* Xs = (unsigned short*)XsU;
    const int t = threadIdx.x, tc = t & 15;
    const int l = t & 63, w = t >> 6, lr = l & 15, q = l >> 4;

    float sc[8], sh[8];
#pragma unroll
    for (int j = 0; j < 8; ++j) { sc[j] = ss[tc * 8 + j]; sh[j] = ss[128 + tc * 8 + j]; }

    bf16x8 Bf[4][3];
#pragma unroll
    for (int kt = 0; kt < 4; ++kt)
#pragma unroll
        for (int n = 0; n < 3; ++n)
            Bf[kt][n] = *(const bf16x8*)&((const uint4*)Wt)[(kt * 4 + q) * 48 + n * 16 + lr];

    for (int tile = blockIdx.x; tile < ntiles; tile += gridDim.x) {
        const int row0 = tile * 64;
        __syncthreads();
#pragma unroll
        for (int k2 = 0; k2 < 4; ++k2) {
            int row = (t >> 4) + k2 * 16;
            int grow = row0 + row;
            uint4 u = ((const uint4*)(srcp + (size_t)grow * FEAT))[tc];
            float v0 = fmaxf(fmaf(bflo(u.x), sc[0], sh[0]), 0.f);
            float v1 = fmaxf(fmaf(bfhi(u.x), sc[1], sh[1]), 0.f);
            float v2 = fmaxf(fmaf(bflo(u.y), sc[2], sh[2]), 0.f);
            float v3 = fmaxf(fmaf(bfhi(u.y), sc[3], sh[3]), 0.f);
            float v4 = fmaxf(fmaf(bflo(u.z), sc[4], sh[4]), 0.f);
            float v5 = fmaxf(fmaf(bfhi(u.z), sc[5], sh[5]), 0.f);
            float v6 = fmaxf(fmaf(bflo(u.w), sc[6], sh[6]), 0.f);
            float v7 = fmaxf(fmaf(bfhi(u.w), sc[7], sh[7]), 0.f);
            uint4 o;
            o.x = packbf2(v0, v1); o.y = packbf2(v2, v3);
            o.z = packbf2(v4, v5); o.w = packbf2(v6, v7);
            XsU[row * 16 + (tc ^ (row & 7))] = o;
        }
        __syncthreads();

        f32x4 acc[3];
#pragma unroll
        for (int n = 0; n < 3; ++n)
#pragma unroll
            for (int r2 = 0; r2 < 4; ++r2) acc[n][r2] = 0.f;

#pragma unroll
        for (int kt = 0; kt < 4; ++kt) {
            int row = w * 16 + lr;
            bf16x8 A = *(const bf16x8*)&XsU[row * 16 + ((kt * 4 + q) ^ (row & 7))];
#pragma unroll
            for (int n = 0; n < 3; ++n)
                acc[n] = __builtin_amdgcn_mfma_f32_16x16x32_bf16(A, Bf[kt][n], acc[n], 0, 0, 0);
        }
        __syncthreads();

        float dv[4];
#pragma unroll
        for (int r = 0; r < 4; ++r) dv[r] = dinv[row0 + w * 16 + q * 4 + r];
#pragma unroll
        for (int n = 0; n < 3; ++n) {
            int col = n * 16 + lr;
#pragma unroll
            for (int r = 0; r < 4; ++r) {
                int row = w * 16 + q * 4 + r;
                Xs[row * 128 + (((col >> 3) ^ (row & 7)) << 3) + (col & 7)] = f2bf(acc[n][r] * dv[r]);
            }
        }
        __syncthreads();
        for (int i = t; i < 384; i += 256) {
            int row = i / 6, cc = i - row * 6;
            ((uint4*)&H3[(size_t)(row0 + row) * 64])[cc] = XsU[row * 16 + (cc ^ (row & 7))];
        }
    }
}

// ---------------- aggregation: 16-lane group, 2 sequential nodes, BRANCHLESS dup-tail gathers ----------------

__global__ __launch_bounds__(256) void agg128_k(const uint4* __restrict__ Hb4, const int* __restrict__ offs,
                                                const int* __restrict__ csr, const float* __restrict__ dinv,
                                                const float* __restrict__ bias, uint4* __restrict__ Zb4,
                                                float* __restrict__ sums, int n) {
    const int t = threadIdx.x;
    const int g16 = t >> 4, l16 = t & 15;
    const int wid = t >> 6, l = t & 63;

    float bs[8];
#pragma unroll
    for (int j = 0; j < 8; ++j) bs[j] = bias[l16 * 8 + j];
    float s[8] = {0.f,0.f,0.f,0.f,0.f,0.f,0.f,0.f};
    float qq[8] = {0.f,0.f,0.f,0.f,0.f,0.f,0.f,0.f};

    // prefetch both nodes' metadata up front (hides node-B setup latency under node-A gathers)
    const int nodeA = blockIdx.x * 32 + g16;
    const int nodeB = nodeA + 16;
    const bool vA = nodeA < n, vB = nodeB < n;
    int begA = 0, endA = 0, begB = 0, endB = 0;
    float dvA = 0.f, dvB = 0.f;
    if (vA) { begA = offs[nodeA]; endA = offs[nodeA + 1]; dvA = dinv[nodeA]; }
    if (vB) { begB = offs[nodeB]; endB = offs[nodeB + 1]; dvB = dinv[nodeB]; }

#pragma unroll
    for (int half = 0; half < 2; ++half) {
        const int node = half ? nodeB : nodeA;
        const int beg = half ? begB : begA;
        const int end = half ? endB : endA;
        const float dv = half ? dvB : dvA;
        if (half ? vB : vA) {
            uint4 u = Hb4[(size_t)node * 16 + l16];
            float a[8];
            a[0]=bflo(u.x); a[1]=bfhi(u.x); a[2]=bflo(u.y); a[3]=bfhi(u.y);
            a[4]=bflo(u.z); a[5]=bfhi(u.z); a[6]=bflo(u.w); a[7]=bfhi(u.w);
            float a2[8] = {0.f,0.f,0.f,0.f,0.f,0.f,0.f,0.f};
            for (int e = beg; e < end; e += 8) {
                int rem = end - e;   // >= 1
                int s0 = csr[e];
                int s1 = (rem > 1) ? csr[e + 1] : s0;
                int s2 = (rem > 2) ? csr[e + 2] : s0;
                int s3 = (rem > 3) ? csr[e + 3] : s0;
                int s4 = (rem > 4) ? csr[e + 4] : s0;
                int s5 = (rem > 5) ? csr[e + 5] : s0;
                int s6 = (rem > 6) ? csr[e + 6] : s0;
                int s7 = (rem > 7) ? csr[e + 7] : s0;
                uint4 g0 = Hb4[(size_t)s0 * 16 + l16];
                uint4 g1 = Hb4[(size_t)s1 * 16 + l16];
                uint4 g2 = Hb4[(size_t)s2 * 16 + l16];
                uint4 g3 = Hb4[(size_t)s3 * 16 + l16];
                uint4 g4 = Hb4[(size_t)s4 * 16 + l16];
                uint4 g5 = Hb4[(size_t)s5 * 16 + l16];
                uint4 g6 = Hb4[(size_t)s6 * 16 + l16];
                uint4 g7 = Hb4[(size_t)s7 * 16 + l16];
#define ACCM(dst, v, c) { dst[0]+= (c)?bflo(v.x):0.f; dst[1]+= (c)?bfhi(v.x):0.f; \
                          dst[2]+= (c)?bflo(v.y):0.f; dst[3]+= (c)?bfhi(v.y):0.f; \
                          dst[4]+= (c)?bflo(v.z):0.f; dst[5]+= (c)?bfhi(v.z):0.f; \
                          dst[6]+= (c)?bflo(v.w):0.f; dst[7]+= (c)?bfhi(v.w):0.f; }
                ACCM(a,  g0, true);
                ACCM(a2, g1, rem > 1);
                ACCM(a,  g2, rem > 2);
                ACCM(a2, g3, rem > 3);
                ACCM(a,  g4, rem > 4);
                ACCM(a2, g5, rem > 5);
                ACCM(a,  g6, rem > 6);
                ACCM(a2, g7, rem > 7);
#undef ACCM
            }
            float z[8];
#pragma unroll
            for (int j = 0; j < 8; ++j) {
                z[j] = fmaf(a[j] + a2[j], dv, bs[j]);
                s[j] += z[j];
                qq[j] += z[j] * z[j];
            }
            uint4 o;
            o.x = packbf2(z[0], z[1]); o.y = packbf2(z[2], z[3]);
            o.z = packbf2(z[4], z[5]); o.w = packbf2(z[6], z[7]);
            Zb4[(size_t)node * 16 + l16] = o;
        }
    }

    // BN stats: cross-group shfl reduce, then tiny LDS + one atomic per feature per block
#pragma unroll
    for (int j = 0; j < 8; ++j) {
        s[j] += __shfl_xor(s[j], 16);
        s[j] += __shfl_xor(s[j], 32);
        qq[j] += __shfl_xor(qq[j], 16);
        qq[j] += __shfl_xor(qq[j], 32);
    }
    __shared__ float red[4][16][16];   // [wave][l16][8 sum | 8 sq]
    if (l < 16) {
#pragma unroll
        for (int j = 0; j < 8; ++j) {
            red[wid][l][j] = s[j];
            red[wid][l][8 + j] = qq[j];
        }
    }
    __syncthreads();
    int f = t & 127, which = t >> 7;
    float acc = 0.f;
#pragma unroll
    for (int ww = 0; ww < 4; ++ww) acc += red[ww][f >> 3][which * 8 + (f & 7)];
    atomicAdd(&sums[which * 128 + f], acc);
}

__global__ void bnfinal_k(const float* __restrict__ sums, const float* __restrict__ g,
                          const float* __restrict__ be, float* __restrict__ ss, int n) {
    int c = threadIdx.x;
    float inv_n = 1.0f / (float)n;
    float mu = sums[c] * inv_n;
    float var = sums[128 + c] * inv_n - mu * mu;
    float rstd = rsqrtf(var + BN_EPS);
    float scv = g[c] * rstd;
    ss[c] = scv;
    ss[128 + c] = be[c] - mu * scv;
}

// ---------------- layer-3 aggregation: 8-lane group per node, branchless dup-tail gathers ----------------

__global__ __launch_bounds__(256) void agg40_k(const uint4* __restrict__ H34, const int* __restrict__ offs,
                                               const int* __restrict__ csr, const float* __restrict__ dinv,
                                               const float* __restrict__ bias, float* __restrict__ out, int n) {
    const int t = threadIdx.x;
    const int g8 = t >> 3, l8 = t & 7;     // 32 groups/block; lane covers cols l8*8..+7
    const int node = blockIdx.x * 32 + g8;
    if (node >= n) return;                 // whole 8-lane group exits together

    int beg = offs[node], end = offs[node + 1];
    uint4 u = H34[(size_t)node * 8 + l8];
    float a[8];
    a[0]=bflo(u.x); a[1]=bfhi(u.x); a[2]=bflo(u.y); a[3]=bfhi(u.y);
    a[4]=bflo(u.z); a[5]=bfhi(u.z); a[6]=bflo(u.w); a[7]=bfhi(u.w);
    float a2[8] = {0.f,0.f,0.f,0.f,0.f,0.f,0.f,0.f};

    for (int e = beg; e < end; e += 8) {
        int rem = end - e;
        int s0 = csr[e];
        int s1 = (rem > 1) ? csr[e + 1] : s0;
        int s2 = (rem > 2) ? csr[e + 2] : s0;
        int s3 = (rem > 3) ? csr[e + 3] : s0;
        int s4 = (rem > 4) ? csr[e + 4] : s0;
        int s5 = (rem > 5) ? csr[e + 5] : s0;
        int s6 = (rem > 6) ? csr[e + 6] : s0;
        int s7 = (rem > 7) ? csr[e + 7] : s0;
        uint4 v0 = H34[(size_t)s0 * 8 + l8];
        uint4 v1 = H34[(size_t)s1 * 8 + l8];
        uint4 v2 = H34[(size_t)s2 * 8 + l8];
        uint4 v3 = H34[(size_t)s3 * 8 + l8];
        uint4 v4 = H34[(size_t)s4 * 8 + l8];
        uint4 v5 = H34[(size_t)s5 * 8 + l8];
        uint4 v6 = H34[(size_t)s6 * 8 + l8];
        uint4 v7 = H34[(size_t)s7 * 8 + l8];
#define ACCM(dst, v, c) { dst[0]+= (c)?bflo(v.x):0.f; dst[1]+= (c)?bfhi(v.x):0.f; \
                          dst[2]+= (c)?bflo(v.y):0.f; dst[3]+= (c)?bfhi(v.y):0.f; \
                          dst[4]+= (c)?bflo(v.z):0.f; dst[5]+= (c)?bfhi(v.z):0.f; \
                          dst[6]+= (c)?bflo(v.w):0.f; dst[7]+= (c)?bfhi(v.w):0.f; }
        ACCM(a,  v0, true);
        ACCM(a2, v1, rem > 1);
        ACCM(a,  v2, rem > 2);
        ACCM(a2, v3, rem > 3);
        ACCM(a,  v4, rem > 4);
        ACCM(a2, v5, rem > 5);
        ACCM(a,  v6, rem > 6);
        ACCM(a2, v7, rem > 7);
#undef ACCM
    }

    float dv = dinv[node];
    float val[8];
    float m = -INFINITY;
#pragma unroll
    for (int j = 0; j < 8; ++j) {
        int fj = l8 * 8 + j;
        val[j] = (fj < FOUT) ? fmaf(a[j] + a2[j], dv, bias[fj]) : -INFINITY;
        m = fmaxf(m, val[j]);
    }
#pragma unroll
    for (int o = 4; o > 0; o >>= 1) m = fmaxf(m, __shfl_xor(m, o, 8));
    float es = 0.f;
#pragma unroll
    for (int j = 0; j < 8; ++j) es += (l8 * 8 + j < FOUT) ? expf(val[j] - m) : 0.f;
#pragma unroll
    for (int o = 4; o > 0; o >>= 1) es += __shfl_xor(es, o, 8);
    float lse = m + logf(es);
    if (l8 < 5) {
        float4 o0 = make_float4(val[0]-lse, val[1]-lse, val[2]-lse, val[3]-lse);
        float4 o1 = make_float4(val[4]-lse, val[5]-lse, val[6]-lse, val[7]-lse);
        float* op = out + (size_t)node * FOUT + l8 * 8;
        *(float4*)op = o0;
        *(float4*)(op + 4) = o1;
    }
}

// ---------------- launch ----------------

extern "C" void kernel_launch(void* const* d_in, const int* in_sizes, int n_in,
                              void* d_out, int out_size, void* d_ws, size_t ws_size,
                              hipStream_t stream) {
    const float* x   = (const float*)d_in[0];
    const int*   src = (const int*)d_in[1];
    const int*   dst = (const int*)d_in[2];
    const float* W1  = (const float*)d_in[3];
    const float* b1  = (const float*)d_in[4];
    const float* W2  = (const float*)d_in[5];
    const float* b2  = (const float*)d_in[6];
    const float* W3  = (const float*)d_in[7];
    const float* b3  = (const float*)d_in[8];
    const float* g1  = (const float*)d_in[9];
    const float* be1 = (const float*)d_in[10];
    const float* g2  = (const float*)d_in[11];
    const float* be2 = (const float*)d_in[12];

    const int N = in_sizes[0] / FEAT;
    const int E = in_sizes[1];
    const int Np = (N + 63) & ~63;
    const int ntiles = Np / 64;
    float* out = (float*)d_out;

    char* p = (char*)d_ws;
    auto alloc = [&](size_t bytes) {
        char* r = p;
        p += (bytes + 255) & ~(size_t)255;
        return r;
    };
    float* dinv   = (float*)alloc((size_t)Np * 4);
    int*   cnt    = (int*)alloc((size_t)N * 4);
    int*   offs   = (int*)alloc((size_t)(N + 1) * 4);
    int*   cursor = (int*)alloc((size_t)N * 4);
    int*   csr    = (int*)alloc((size_t)E * 4);
    int*   bsum   = (int*)alloc(1024);
    int*   boff   = (int*)alloc(1024);
    float* sums   = (float*)alloc(1024);
    float* ss     = (float*)alloc(1024);
    unsigned short* Wt1 = (unsigned short*)alloc(4 * 4 * 128 * 8 * 2);
    unsigned short* Wt2 = (unsigned short*)alloc(4 * 4 * 128 * 8 * 2);
    unsigned short* Wt3 = (unsigned short*)alloc(4 * 4 * 48 * 8 * 2);
    unsigned short* Hb  = (unsigned short*)alloc((size_t)Np * FEAT * 2);
    unsigned short* Zb  = (unsigned short*)alloc((size_t)Np * FEAT * 2);
    unsigned short* H3  = (unsigned short*)alloc((size_t)Np * 64 * 2);

    const int nb = (N + 1023) / 1024;
    const int eb = (E + 255) / 256;
    const int ab = (N + 31) / 32;   // 32 nodes per block for both agg kernels

    // CSR build + dinv
    hipMemsetAsync(cnt, 0, (size_t)N * 4, stream);
    count_k<<<eb, 256, 0, stream>>>(dst, cnt, E);
    scan1_k<<<nb, 256, 0, stream>>>(cnt, bsum, N);
    scan2_k<<<1, 256, 0, stream>>>(bsum, boff, nb, offs, N, E);
    scan3_k<<<nb, 256, 0, stream>>>(cnt, boff, offs, cursor, dinv, N);
    fill_k<<<eb, 256, 0, stream>>>(src, dst, cursor, csr, E);
    castW_k<<<48, 256, 0, stream>>>(W1, W2, W3, Wt1, Wt2, Wt3);

    // Layer 1
    gemm128_k<0><<<768, 256, 0, stream>>>(x, Wt1, nullptr, dinv, Hb, ntiles, N);
    hipMemsetAsync(sums, 0, 1024, stream);
    agg128_k<<<ab, 256, 0, stream>>>((const uint4*)Hb, offs, csr, dinv, b1, (uint4*)Zb, sums, N);
    bnfinal_k<<<1, 128, 0, stream>>>(sums, g1, be1, ss, N);

    // Layer 2 (BN1+ReLU fused into staging)
    gemm128_k<1><<<768, 256, 0, stream>>>(Zb, Wt2, ss, dinv, Hb, ntiles, N);
    hipMemsetAsync(sums, 0, 1024, stream);
    agg128_k<<<ab, 256, 0, stream>>>((const uint4*)Hb, offs, csr, dinv, b2, (uint4*)Zb, sums, N);
    bnfinal_k<<<1, 128, 0, stream>>>(sums, g2, be2, ss, N);

    // Layer 3 (BN2+ReLU fused into staging) + log_softmax
    gemm40_k<<<1024, 256, 0, stream>>>(Zb, Wt3, ss, dinv, H3, ntiles);
    agg40_k<<<ab, 256, 0, stream>>>((const uint4*)H3, offs, csr, dinv, b3, out, N);
}

// Round 10
// 296.576 us; speedup vs baseline: 1.4590x; 1.1326x over previous
//
#include <hip/hip_runtime.h>
#include <cstdint>
#include <cstddef>

#define FEAT 128
#define FOUT 40
constexpr float BN_EPS = 1e-5f;

typedef __attribute__((ext_vector_type(8))) short bf16x8;
typedef __attribute__((ext_vector_type(4))) float f32x4;

__device__ __forceinline__ unsigned short f2bf(float f) {
    unsigned u = __float_as_uint(f);
    u += 0x7FFFu + ((u >> 16) & 1u);
    return (unsigned short)(u >> 16);
}
__device__ __forceinline__ float bflo(unsigned u) { return __uint_as_float(u << 16); }
__device__ __forceinline__ float bfhi(unsigned u) { return __uint_as_float(u & 0xFFFF0000u); }
__device__ __forceinline__ unsigned packbf2(float a, float b) {
    return (unsigned)f2bf(a) | ((unsigned)f2bf(b) << 16);
}

// ---------------- CSR build ----------------

__global__ __launch_bounds__(256) void count_k(const int* __restrict__ dst, int* __restrict__ cnt, int E) {
    int e = blockIdx.x * 256 + threadIdx.x;
    if (e < E) atomicAdd(&cnt[dst[e]], 1);
}

__global__ __launch_bounds__(256) void scan1_k(const int* __restrict__ cnt, int* __restrict__ bsum, int n) {
    __shared__ int sh[256];
    int base = blockIdx.x * 1024, t = threadIdx.x;
    int s = 0;
#pragma unroll
    for (int j = 0; j < 4; ++j) {
        int idx = base + t * 4 + j;
        if (idx < n) s += cnt[idx];
    }
    sh[t] = s;
    __syncthreads();
    for (int o = 128; o > 0; o >>= 1) {
        if (t < o) sh[t] += sh[t + o];
        __syncthreads();
    }
    if (t == 0) bsum[blockIdx.x] = sh[0];
}

__global__ void scan2_k(const int* __restrict__ bsum, int* __restrict__ boff, int nb,
                        int* __restrict__ offs, int n, int E) {
    __shared__ int sh[256];
    int t = threadIdx.x;
    if (nb <= 256) {
        int v = (t < nb) ? bsum[t] : 0;
        sh[t] = v;
        __syncthreads();
        for (int o = 1; o < 256; o <<= 1) {
            int x = (t >= o) ? sh[t - o] : 0;
            __syncthreads();
            sh[t] += x;
            __syncthreads();
        }
        if (t < nb) boff[t] = sh[t] - v;
        if (t == 0) offs[n] = E;
    } else if (t == 0) {
        int run = 0;
        for (int i = 0; i < nb; ++i) { boff[i] = run; run += bsum[i]; }
        offs[n] = E;
    }
}

// scan3 also emits cursor and dinv
__global__ __launch_bounds__(256) void scan3_k(const int* __restrict__ cnt, const int* __restrict__ boff,
                                               int* __restrict__ offs, int* __restrict__ cursor,
                                               float* __restrict__ dinv, int n) {
    __shared__ int sh[256];
    int base = blockIdx.x * 1024, t = threadIdx.x;
    int c[4];
    int s = 0;
#pragma unroll
    for (int j = 0; j < 4; ++j) {
        int idx = base + t * 4 + j;
        c[j] = (idx < n) ? cnt[idx] : 0;
        s += c[j];
    }
    sh[t] = s;
    __syncthreads();
    for (int o = 1; o < 256; o <<= 1) {
        int v = (t >= o) ? sh[t - o] : 0;
        __syncthreads();
        sh[t] += v;
        __syncthreads();
    }
    int g = boff[blockIdx.x] + sh[t] - s;
#pragma unroll
    for (int j = 0; j < 4; ++j) {
        int idx = base + t * 4 + j;
        if (idx < n) {
            offs[idx] = g;
            cursor[idx] = g;
            dinv[idx] = rsqrtf((float)(c[j] + 1));
        }
        g += c[j];
    }
}

__global__ __launch_bounds__(256) void fill_k(const int* __restrict__ src, const int* __restrict__ dst,
                                              int* __restrict__ cursor, int* __restrict__ csr, int E) {
    int e = blockIdx.x * 256 + threadIdx.x;
    if (e < E) {
        int d = dst[e];
        int p = atomicAdd(&cursor[d], 1);
        csr[p] = src[e];
    }
}

// ---------------- weight pack to bf16 MFMA B-fragment order ----------------

__global__ __launch_bounds__(256) void castW_k(const float* __restrict__ W1, const float* __restrict__ W2,
                                               const float* __restrict__ W3,
                                               unsigned short* __restrict__ Wt1, unsigned short* __restrict__ Wt2,
                                               unsigned short* __restrict__ Wt3) {
    int tid = blockIdx.x * 256 + threadIdx.x;
    int stride = gridDim.x * 256;
    for (int i = tid; i < 4 * 4 * 128 * 8; i += stride) {
        int j = i & 7, c = (i >> 3) & 127, q = (i >> 10) & 3, kt = i >> 12;
        int k = kt * 32 + q * 8 + j;
        Wt1[i] = f2bf(W1[k * 128 + c]);
        Wt2[i] = f2bf(W2[k * 128 + c]);
    }
    for (int i = tid; i < 4 * 4 * 48 * 8; i += stride) {
        int j = i & 7, rest = i >> 3;
        int c = rest % 48, kq = rest / 48;
        int q = kq & 3, kt = kq >> 2;
        int k = kt * 32 + q * 8 + j;
        Wt3[i] = (c < FOUT) ? f2bf(W3[k * FOUT + c]) : (unsigned short)0;
    }
}

// ---------------- MFMA GEMM 128x128, epilogue * dinv, bf16 out ----------------

template <int SRC>
__global__ __launch_bounds__(256, 3) void gemm128_k(const void* __restrict__ srcp,
                                                    const unsigned short* __restrict__ Wt,
                                                    const float* __restrict__ ss,
                                                    const float* __restrict__ dinv,
                                                    unsigned short* __restrict__ Hb,
                                                    int ntiles, int nreal) {
    __shared__ uint4 XsU[64 * 16];
    unsigned short* Xs = (unsigned short*)XsU;

    const int t = threadIdx.x;
    const int tc = t & 15;
    const int l = t & 63, w = t >> 6;
    const int wm = w >> 1, wn = w & 1;
    const int lr = l & 15, q = l >> 4;

    float sc[8], sh[8];
    if (SRC == 1) {
#pragma unroll
        for (int j = 0; j < 8; ++j) { sc[j] = ss[tc * 8 + j]; sh[j] = ss[128 + tc * 8 + j]; }
    }

    bf16x8 Bf[4][4];
#pragma unroll
    for (int kt = 0; kt < 4; ++kt)
#pragma unroll
        for (int n = 0; n < 4; ++n) {
            int col = wn * 64 + n * 16 + lr;
            Bf[kt][n] = *(const bf16x8*)&((const uint4*)Wt)[(kt * 4 + q) * 128 + col];
        }

    for (int tile = blockIdx.x; tile < ntiles; tile += gridDim.x) {
        const int row0 = tile * 64;
        __syncthreads();
#pragma unroll
        for (int k2 = 0; k2 < 4; ++k2) {
            int row = (t >> 4) + k2 * 16;
            int grow = row0 + row;
            uint4 o;
            if (SRC == 0) {
                if (grow < nreal) {
                    const float4* xp = (const float4*)((const float*)srcp + (size_t)grow * FEAT + tc * 8);
                    float4 f0 = xp[0], f1 = xp[1];
                    o.x = packbf2(f0.x, f0.y); o.y = packbf2(f0.z, f0.w);
                    o.z = packbf2(f1.x, f1.y); o.w = packbf2(f1.z, f1.w);
                } else {
                    o.x = 0u; o.y = 0u; o.z = 0u; o.w = 0u;
                }
            } else {
                uint4 u = ((const uint4*)((const unsigned short*)srcp + (size_t)grow * FEAT))[tc];
                float v0 = fmaxf(fmaf(bflo(u.x), sc[0], sh[0]), 0.f);
                float v1 = fmaxf(fmaf(bfhi(u.x), sc[1], sh[1]), 0.f);
                float v2 = fmaxf(fmaf(bflo(u.y), sc[2], sh[2]), 0.f);
                float v3 = fmaxf(fmaf(bfhi(u.y), sc[3], sh[3]), 0.f);
                float v4 = fmaxf(fmaf(bflo(u.z), sc[4], sh[4]), 0.f);
                float v5 = fmaxf(fmaf(bfhi(u.z), sc[5], sh[5]), 0.f);
                float v6 = fmaxf(fmaf(bflo(u.w), sc[6], sh[6]), 0.f);
                float v7 = fmaxf(fmaf(bfhi(u.w), sc[7], sh[7]), 0.f);
                o.x = packbf2(v0, v1); o.y = packbf2(v2, v3);
                o.z = packbf2(v4, v5); o.w = packbf2(v6, v7);
            }
            XsU[row * 16 + (tc ^ (row & 7))] = o;
        }
        __syncthreads();

        f32x4 acc[2][4];
#pragma unroll
        for (int m = 0; m < 2; ++m)
#pragma unroll
            for (int n = 0; n < 4; ++n)
#pragma unroll
                for (int r2 = 0; r2 < 4; ++r2) acc[m][n][r2] = 0.f;

#pragma unroll
        for (int kt = 0; kt < 4; ++kt) {
            int rowA = wm * 32 + lr;
            bf16x8 A0 = *(const bf16x8*)&XsU[rowA * 16 + ((kt * 4 + q) ^ (rowA & 7))];
            int rowB = rowA + 16;
            bf16x8 A1 = *(const bf16x8*)&XsU[rowB * 16 + ((kt * 4 + q) ^ (rowB & 7))];
#pragma unroll
            for (int n = 0; n < 4; ++n) {
                acc[0][n] = __builtin_amdgcn_mfma_f32_16x16x32_bf16(A0, Bf[kt][n], acc[0][n], 0, 0, 0);
                acc[1][n] = __builtin_amdgcn_mfma_f32_16x16x32_bf16(A1, Bf[kt][n], acc[1][n], 0, 0, 0);
            }
        }
        __syncthreads();

#pragma unroll
        for (int m = 0; m < 2; ++m) {
            float dv[4];
#pragma unroll
            for (int r = 0; r < 4; ++r) dv[r] = dinv[row0 + wm * 32 + m * 16 + q * 4 + r];
#pragma unroll
            for (int n = 0; n < 4; ++n) {
                int col = wn * 64 + n * 16 + lr;
#pragma unroll
                for (int r = 0; r < 4; ++r) {
                    int row = wm * 32 + m * 16 + q * 4 + r;
                    Xs[row * 128 + (((col >> 3) ^ (row & 7)) << 3) + (col & 7)] = f2bf(acc[m][n][r] * dv[r]);
                }
            }
        }
        __syncthreads();
#pragma unroll
        for (int k2 = 0; k2 < 4; ++k2) {
            int row = (t >> 4) + k2 * 16;
            ((uint4*)&Hb[(size_t)(row0 + row) * FEAT])[tc] = XsU[row * 16 + (tc ^ (row & 7))];
        }
    }
}

// ---------------- MFMA GEMM 128x40 (padded to 48), fused BN+ReLU on load ----------------

__global__ __launch_bounds__(256, 4) void gemm40_k(const unsigned short* __restrict__ srcp,
                                                   const unsigned short* __restrict__ Wt,
                                                   const float* __restrict__ ss,
                                                   const float* __restrict__ dinv,
                                                   unsigned short* __restrict__ H3,
                                                   int ntiles) {
    __shared__ uint4 XsU[64 * 16];
    unsigned short* Xs = (unsigned short*)XsU;
    const int t = threadIdx.x, tc = t & 15;
    const int l = t & 63, w = t >> 6, lr = l & 15, q = l >> 4;

    float sc[8], sh[8];
#pragma unroll
    for (int j = 0; j < 8; ++j) { sc[j] = ss[tc * 8 + j]; sh[j] = ss[128 + tc * 8 + j]; }

    bf16x8 Bf[4][3];
#pragma unroll
    for (int kt = 0; kt < 4; ++kt)
#pragma unroll
        for (int n = 0; n < 3; ++n)
            Bf[kt][n] = *(const bf16x8*)&((const uint4*)Wt)[(kt * 4 + q) * 48 + n * 16 + lr];

    for (int tile = blockIdx.x; tile < ntiles; tile += gridDim.x) {
        const int row0 = tile * 64;
        __syncthreads();
#pragma unroll
        for (int k2 = 0; k2 < 4; ++k2) {
            int row = (t >> 4) + k2 * 16;
            int grow = row0 + row;
            uint4 u = ((const uint4*)(srcp + (size_t)grow * FEAT))[tc];
            float v0 = fmaxf(fmaf(bflo(u.x), sc[0], sh[0]), 0.f);
            float v1 = fmaxf(fmaf(bfhi(u.x), sc[1], sh[1]), 0.f);
            float v2 = fmaxf(fmaf(bflo(u.y), sc[2], sh[2]), 0.f);
            float v3 = fmaxf(fmaf(bfhi(u.y), sc[3], sh[3]), 0.f);
            float v4 = fmaxf(fmaf(bflo(u.z), sc[4], sh[4]), 0.f);
            float v5 = fmaxf(fmaf(bfhi(u.z), sc[5], sh[5]), 0.f);
            float v6 = fmaxf(fmaf(bflo(u.w), sc[6], sh[6]), 0.f);
            float v7 = fmaxf(fmaf(bfhi(u.w), sc[7], sh[7]), 0.f);
            uint4 o;
            o.x = packbf2(v0, v1); o.y = packbf2(v2, v3);
            o.z = packbf2(v4, v5); o.w = packbf2(v6, v7);
            XsU[row * 16 + (tc ^ (row & 7))] = o;
        }
        __syncthreads();

        f32x4 acc[3];
#pragma unroll
        for (int n = 0; n < 3; ++n)
#pragma unroll
            for (int r2 = 0; r2 < 4; ++r2) acc[n][r2] = 0.f;

#pragma unroll
        for (int kt = 0; kt < 4; ++kt) {
            int row = w * 16 + lr;
            bf16x8 A = *(const bf16x8*)&XsU[row * 16 + ((kt * 4 + q) ^ (row & 7))];
#pragma unroll
            for (int n = 0; n < 3; ++n)
                acc[n] = __builtin_amdgcn_mfma_f32_16x16x32_bf16(A, Bf[kt][n], acc[n], 0, 0, 0);
        }
        __syncthreads();

        float dv[4];
#pragma unroll
        for (int r = 0; r < 4; ++r) dv[r] = dinv[row0 + w * 16 + q * 4 + r];
#pragma unroll
        for (int n = 0; n < 3; ++n) {
            int col = n * 16 + lr;
#pragma unroll
            for (int r = 0; r < 4; ++r) {
                int row = w * 16 + q * 4 + r;
                Xs[row * 128 + (((col >> 3) ^ (row & 7)) << 3) + (col & 7)] = f2bf(acc[n][r] * dv[r]);
            }
        }
        __syncthreads();
        for (int i = t; i < 384; i += 256) {
            int row = i / 6, cc = i - row * 6;
            ((uint4*)&H3[(size_t)(row0 + row) * 64])[cc] = XsU[row * 16 + (cc ^ (row & 7))];
        }
    }
}

// ---------------- aggregation: R5 structure — 16-lane group/node, grid-stride, dup-tail loads ----------------

__global__ __launch_bounds__(256) void agg128_k(const uint4* __restrict__ Hb4, const int* __restrict__ offs,
                                                const int* __restrict__ csr, const float* __restrict__ dinv,
                                                const float* __restrict__ bias, uint4* __restrict__ Zb4,
                                                float* __restrict__ sums, int n) {
    const int t = threadIdx.x;
    const int g16 = t >> 4;        // group 0..15 in block
    const int l16 = t & 15;        // lane in group; features l16*8 .. +7
    float bs[8];
#pragma unroll
    for (int j = 0; j < 8; ++j) bs[j] = bias[l16 * 8 + j];
    float s[8] = {0.f,0.f,0.f,0.f,0.f,0.f,0.f,0.f};
    float qq[8] = {0.f,0.f,0.f,0.f,0.f,0.f,0.f,0.f};

    for (int node = blockIdx.x * 16 + g16; node < n; node += gridDim.x * 16) {
        int beg = offs[node], end = offs[node + 1];
        uint4 u = Hb4[(size_t)node * 16 + l16];
        float a[8];
        a[0] = bflo(u.x); a[1] = bfhi(u.x); a[2] = bflo(u.y); a[3] = bfhi(u.y);
        a[4] = bflo(u.z); a[5] = bfhi(u.z); a[6] = bflo(u.w); a[7] = bfhi(u.w);
        for (int e = beg; e < end; e += 8) {
            int rem = end - e;            // >= 1
            int s0 = csr[e];
            int s1 = (rem > 1) ? csr[e + 1] : s0;
            int s2 = (rem > 2) ? csr[e + 2] : s0;
            int s3 = (rem > 3) ? csr[e + 3] : s0;
            int s4 = (rem > 4) ? csr[e + 4] : s0;
            int s5 = (rem > 5) ? csr[e + 5] : s0;
            int s6 = (rem > 6) ? csr[e + 6] : s0;
            int s7 = (rem > 7) ? csr[e + 7] : s0;
            uint4 v0 = Hb4[(size_t)s0 * 16 + l16];
            uint4 v1 = Hb4[(size_t)s1 * 16 + l16];
            uint4 v2 = Hb4[(size_t)s2 * 16 + l16];
            uint4 v3 = Hb4[(size_t)s3 * 16 + l16];
            uint4 v4 = Hb4[(size_t)s4 * 16 + l16];
            uint4 v5 = Hb4[(size_t)s5 * 16 + l16];
            uint4 v6 = Hb4[(size_t)s6 * 16 + l16];
            uint4 v7 = Hb4[(size_t)s7 * 16 + l16];
#define ACC8(v) { a[0]+=bflo(v.x); a[1]+=bfhi(v.x); a[2]+=bflo(v.y); a[3]+=bfhi(v.y); \
                  a[4]+=bflo(v.z); a[5]+=bfhi(v.z); a[6]+=bflo(v.w); a[7]+=bfhi(v.w); }
            ACC8(v0);
            if (rem > 1) ACC8(v1);
            if (rem > 2) ACC8(v2);
            if (rem > 3) ACC8(v3);
            if (rem > 4) ACC8(v4);
            if (rem > 5) ACC8(v5);
            if (rem > 6) ACC8(v6);
            if (rem > 7) ACC8(v7);
#undef ACC8
        }
        float dv = dinv[node];
        float z[8];
#pragma unroll
        for (int j = 0; j < 8; ++j) {
            z[j] = fmaf(a[j], dv, bs[j]);
            s[j] += z[j];
            qq[j] += z[j] * z[j];
        }
        uint4 o;
        o.x = packbf2(z[0], z[1]); o.y = packbf2(z[2], z[3]);
        o.z = packbf2(z[4], z[5]); o.w = packbf2(z[6], z[7]);
        Zb4[(size_t)node * 16 + l16] = o;
    }

    // BN stats: per-group partials -> LDS -> one atomic per feature per block
    __shared__ float red[2][16][128];
#pragma unroll
    for (int j = 0; j < 8; ++j) {
        red[0][g16][l16 * 8 + j] = s[j];
        red[1][g16][l16 * 8 + j] = qq[j];
    }
    __syncthreads();
    int f = t & 127, which = t >> 7;
    float acc = 0.f;
#pragma unroll
    for (int G = 0; G < 16; ++G) acc += red[which][G][f];
    atomicAdd(&sums[which * 128 + f], acc);
}

__global__ void bnfinal_k(const float* __restrict__ sums, const float* __restrict__ g,
                          const float* __restrict__ be, float* __restrict__ ss, int n) {
    int c = threadIdx.x;
    float inv_n = 1.0f / (float)n;
    float mu = sums[c] * inv_n;
    float var = sums[128 + c] * inv_n - mu * mu;
    float rstd = rsqrtf(var + BN_EPS);
    float scv = g[c] * rstd;
    ss[c] = scv;
    ss[128 + c] = be[c] - mu * scv;
}

// ---------------- layer-3 aggregation: 8-lane group/node, grid-stride, dup-tail loads ----------------

__global__ __launch_bounds__(256) void agg40_k(const uint4* __restrict__ H34, const int* __restrict__ offs,
                                               const int* __restrict__ csr, const float* __restrict__ dinv,
                                               const float* __restrict__ bias, float* __restrict__ out, int n) {
    const int t = threadIdx.x;
    const int g8 = t >> 3, l8 = t & 7;     // 32 groups/block; lane covers cols l8*8..+7
    float bl[8];
#pragma unroll
    for (int j = 0; j < 8; ++j) {
        int fj = l8 * 8 + j;
        bl[j] = (fj < FOUT) ? bias[fj] : 0.f;
    }

    for (int node = blockIdx.x * 32 + g8; node < n; node += gridDim.x * 32) {
        int beg = offs[node], end = offs[node + 1];
        uint4 u = H34[(size_t)node * 8 + l8];
        float a[8];
        a[0]=bflo(u.x); a[1]=bfhi(u.x); a[2]=bflo(u.y); a[3]=bfhi(u.y);
        a[4]=bflo(u.z); a[5]=bfhi(u.z); a[6]=bflo(u.w); a[7]=bfhi(u.w);

        for (int e = beg; e < end; e += 8) {
            int rem = end - e;
            int s0 = csr[e];
            int s1 = (rem > 1) ? csr[e + 1] : s0;
            int s2 = (rem > 2) ? csr[e + 2] : s0;
            int s3 = (rem > 3) ? csr[e + 3] : s0;
            int s4 = (rem > 4) ? csr[e + 4] : s0;
            int s5 = (rem > 5) ? csr[e + 5] : s0;
            int s6 = (rem > 6) ? csr[e + 6] : s0;
            int s7 = (rem > 7) ? csr[e + 7] : s0;
            uint4 v0 = H34[(size_t)s0 * 8 + l8];
            uint4 v1 = H34[(size_t)s1 * 8 + l8];
            uint4 v2 = H34[(size_t)s2 * 8 + l8];
            uint4 v3 = H34[(size_t)s3 * 8 + l8];
            uint4 v4 = H34[(size_t)s4 * 8 + l8];
            uint4 v5 = H34[(size_t)s5 * 8 + l8];
            uint4 v6 = H34[(size_t)s6 * 8 + l8];
            uint4 v7 = H34[(size_t)s7 * 8 + l8];
#define ACC8(v) { a[0]+=bflo(v.x); a[1]+=bfhi(v.x); a[2]+=bflo(v.y); a[3]+=bfhi(v.y); \
                  a[4]+=bflo(v.z); a[5]+=bfhi(v.z); a[6]+=bflo(v.w); a[7]+=bfhi(v.w); }
            ACC8(v0);
            if (rem > 1) ACC8(v1);
            if (rem > 2) ACC8(v2);
            if (rem > 3) ACC8(v3);
            if (rem > 4) ACC8(v4);
            if (rem > 5) ACC8(v5);
            if (rem > 6) ACC8(v6);
            if (rem > 7) ACC8(v7);
#undef ACC8
        }

        float dv = dinv[node];
        float val[8];
        float m = -INFINITY;
#pragma unroll
        for (int j = 0; j < 8; ++j) {
            int fj = l8 * 8 + j;
            val[j] = (fj < FOUT) ? fmaf(a[j], dv, bl[j]) : -INFINITY;
            m = fmaxf(m, val[j]);
        }
#pragma unroll
        for (int o = 4; o > 0; o >>= 1) m = fmaxf(m, __shfl_xor(m, o, 8));
        float es = 0.f;
#pragma unroll
        for (int j = 0; j < 8; ++j) es += (l8 * 8 + j < FOUT) ? expf(val[j] - m) : 0.f;
#pragma unroll
        for (int o = 4; o > 0; o >>= 1) es += __shfl_xor(es, o, 8);
        float lse = m + logf(es);
        if (l8 < 5) {
            float4 o0 = make_float4(val[0]-lse, val[1]-lse, val[2]-lse, val[3]-lse);
            float4 o1 = make_float4(val[4]-lse, val[5]-lse, val[6]-lse, val[7]-lse);
            float* op = out + (size_t)node * FOUT + l8 * 8;
            *(float4*)op = o0;
            *(float4*)(op + 4) = o1;
        }
    }
}

// ---------------- launch ----------------

extern "C" void kernel_launch(void* const* d_in, const int* in_sizes, int n_in,
                              void* d_out, int out_size, void* d_ws, size_t ws_size,
                              hipStream_t stream) {
    const float* x   = (const float*)d_in[0];
    const int*   src = (const int*)d_in[1];
    const int*   dst = (const int*)d_in[2];
    const float* W1  = (const float*)d_in[3];
    const float* b1  = (const float*)d_in[4];
    const float* W2  = (const float*)d_in[5];
    const float* b2  = (const float*)d_in[6];
    const float* W3  = (const float*)d_in[7];
    const float* b3  = (const float*)d_in[8];
    const float* g1  = (const float*)d_in[9];
    const float* be1 = (const float*)d_in[10];
    const float* g2  = (const float*)d_in[11];
    const float* be2 = (const float*)d_in[12];

    const int N = in_sizes[0] / FEAT;
    const int E = in_sizes[1];
    const int Np = (N + 63) & ~63;
    const int ntiles = Np / 64;
    float* out = (float*)d_out;

    char* p = (char*)d_ws;
    auto alloc = [&](size_t bytes) {
        char* r = p;
        p += (bytes + 255) & ~(size_t)255;
        return r;
    };
    float* dinv   = (float*)alloc((size_t)Np * 4);
    int*   cnt    = (int*)alloc((size_t)N * 4);
    int*   offs   = (int*)alloc((size_t)(N + 1) * 4);
    int*   cursor = (int*)alloc((size_t)N * 4);
    int*   csr    = (int*)alloc((size_t)E * 4);
    int*   bsum   = (int*)alloc(1024);
    int*   boff   = (int*)alloc(1024);
    float* sums   = (float*)alloc(1024);
    float* ss     = (float*)alloc(1024);
    unsigned short* Wt1 = (unsigned short*)alloc(4 * 4 * 128 * 8 * 2);
    unsigned short* Wt2 = (unsigned short*)alloc(4 * 4 * 128 * 8 * 2);
    unsigned short* Wt3 = (unsigned short*)alloc(4 * 4 * 48 * 8 * 2);
    unsigned short* Hb  = (unsigned short*)alloc((size_t)Np * FEAT * 2);
    unsigned short* Zb  = (unsigned short*)alloc((size_t)Np * FEAT * 2);
    unsigned short* H3  = (unsigned short*)alloc((size_t)Np * 64 * 2);

    const int nb = (N + 1023) / 1024;
    const int eb = (E + 255) / 256;

    // CSR build + dinv
    hipMemsetAsync(cnt, 0, (size_t)N * 4, stream);
    count_k<<<eb, 256, 0, stream>>>(dst, cnt, E);
    scan1_k<<<nb, 256, 0, stream>>>(cnt, bsum, N);
    scan2_k<<<1, 256, 0, stream>>>(bsum, boff, nb, offs, N, E);
    scan3_k<<<nb, 256, 0, stream>>>(cnt, boff, offs, cursor, dinv, N);
    fill_k<<<eb, 256, 0, stream>>>(src, dst, cursor, csr, E);
    castW_k<<<48, 256, 0, stream>>>(W1, W2, W3, Wt1, Wt2, Wt3);

    // Layer 1
    gemm128_k<0><<<768, 256, 0, stream>>>(x, Wt1, nullptr, dinv, Hb, ntiles, N);
    hipMemsetAsync(sums, 0, 1024, stream);
    agg128_k<<<2048, 256, 0, stream>>>((const uint4*)Hb, offs, csr, dinv, b1, (uint4*)Zb, sums, N);
    bnfinal_k<<<1, 128, 0, stream>>>(sums, g1, be1, ss, N);

    // Layer 2 (BN1+ReLU fused into staging)
    gemm128_k<1><<<768, 256, 0, stream>>>(Zb, Wt2, ss, dinv, Hb, ntiles, N);
    hipMemsetAsync(sums, 0, 1024, stream);
    agg128_k<<<2048, 256, 0, stream>>>((const uint4*)Hb, offs, csr, dinv, b2, (uint4*)Zb, sums, N);
    bnfinal_k<<<1, 128, 0, stream>>>(sums, g2, be2, ss, N);

    // Layer 3 (BN2+ReLU fused into staging) + log_softmax
    gemm40_k<<<1024, 256, 0, stream>>>(Zb, Wt3, ss, dinv, H3, ntiles);
    agg40_k<<<2048, 256, 0, stream>>>((const uint4*)H3, offs, csr, dinv, b3, out, N);
}